// Round 2
// baseline (1038.282 us; speedup 1.0000x reference)
//
#include <hip/hip_runtime.h>
#include <math.h>

// Problem constants (fixed by the reference)
#define N_SUP 65536
#define E_DIM 512
#define H_HEADS 8
#define C_CLS 64
#define DHD 64
#define L_LEV 3
#define LN_EPS 1e-5f
#define ATTN_SPLITS 8
#define CTX_SPLITS 16
#define SCAT_BLOCKS 256        // N_SUP / 256
#define KV_LD 1024

typedef _Float16 f16x8 __attribute__((ext_vector_type(8)));
typedef _Float16 f16x4 __attribute__((ext_vector_type(4)));
typedef float f32x4 __attribute__((ext_vector_type(4)));

// ---------------------------------------------------------------------------
// async global->LDS copy, 16B per lane (wave-uniform LDS base + lane*16;
// global source address is per-lane).
// ---------------------------------------------------------------------------
__device__ __forceinline__ void gload_lds16(const void* g, void* lds) {
    __builtin_amdgcn_global_load_lds((const __attribute__((address_space(1))) void*)g,
                                     (__attribute__((address_space(3))) void*)lds,
                                     16, 0, 0);
}

// ---------------------------------------------------------------------------
// fp16 GEMM, 256x256 tile, BK=64, 8 waves (2M x 4N), counted-vmcnt pipeline.
//   C[M x Ncols] = A[M x 512] @ B + bias; Bt is B^T [Ncols x 512].
// K fixed at 512 -> 8 K-tiles of 64. Two LDS slots (A+B = 64 KiB each),
// slot t&1 holds tile t. Per tile:
//   vmcnt(8) [tile t's own 8 loads done; t+1's 8 still in flight] -> barrier
//   -> 24x ds_read_b128 (all frags, XOR-swizzled) -> lgkmcnt(0) -> barrier
//   -> stage tile t+2 into the just-freed slot -> 64 MFMA (setprio).
// Swizzle: LDS(row r, 16B-block b) holds global k-block (b ^ (r&7)); read side
// uses blk = (4*kk + q) ^ (m&7) with r&7 == m&7 -> involution cancels. Uniform
// 8 lanes per bank-group per b128 -> conflict-free (same scheme as the BK=32
// kernel that measured SQ_LDS_BANK_CONFLICT = 0).
// Band swizzle on grid.x preserved for A-panel L2 reuse.
// ---------------------------------------------------------------------------
__global__ __launch_bounds__(512, 2)
void hgemm256(const _Float16* __restrict__ A, int lda, size_t aStride,
              const _Float16* __restrict__ Bt, size_t btStride,
              const float* __restrict__ bias, size_t biasStride,
              _Float16* __restrict__ C, int ldc, size_t cStride, int nCol) {
    const int z = blockIdx.y;
    A += z * aStride; Bt += z * btStride; bias += z * biasStride; C += z * cStride;

    const int nRow = gridDim.x / nCol;
    const int R = nRow < 64 ? nRow : 64;
    const int bid = blockIdx.x;
    const int bandSz = R * nCol;
    const int band = bid / bandSz;
    const int rem = bid % bandSz;
    const int colT = rem / R;
    const int rowT = band * R + (rem % R);
    const int row0 = rowT * 256, col0 = colT * 256;

    // [slot][A/B][256 rows][64 f16] = 128 KiB
    __shared__ _Float16 smem[2][2][256][64];

    const int tid = threadIdx.x;
    const int wave = tid >> 6, lane = tid & 63;
    const int wm2 = (wave & 1) * 128;     // M half of this wave
    const int wn4 = (wave >> 1) * 64;     // N quarter of this wave
    const int m = lane & 15, q = lane >> 4;

    // staging: thread -> (row sr in 0..63 per pass, 16B-block sb), swizzled src
    const int sr = tid >> 3;
    const int sb = tid & 7;
    const int sblk = sb ^ (sr & 7);       // r&7 == sr&7 for every pass (p*64)

    const _Float16* Asrc = A + (size_t)(row0 + sr) * lda + sblk * 8;
    const _Float16* Bsrc = Bt + (size_t)(col0 + sr) * E_DIM + sblk * 8;
    const size_t aPass = (size_t)64 * lda;   // 64 rows per pass
    const size_t bPass = (size_t)64 * E_DIM;

#define STAGE_TILE(k0, s)                                                     \
    {                                                                         \
        char* la = (char*)&smem[s][0][0][0] + wave * 1024;                    \
        char* lb = (char*)&smem[s][1][0][0] + wave * 1024;                    \
        _Pragma("unroll")                                                     \
        for (int p = 0; p < 4; ++p)                                           \
            gload_lds16(Asrc + (size_t)p * aPass + (k0), la + p * 8192);      \
        _Pragma("unroll")                                                     \
        for (int p = 0; p < 4; ++p)                                           \
            gload_lds16(Bsrc + (size_t)p * bPass + (k0), lb + p * 8192);      \
    }

    f32x4 acc[8][4];
#pragma unroll
    for (int i = 0; i < 8; ++i)
#pragma unroll
        for (int j = 0; j < 4; ++j) acc[i][j] = (f32x4){0.f, 0.f, 0.f, 0.f};

    // element offsets of the two kk sub-steps (in f16), swizzled
    const int c0k = ((q) ^ (m & 7)) * 8;
    const int c1k = ((4 + q) ^ (m & 7)) * 8;

    // prologue: stage tiles 0 and 1 (8 loads each per thread)
    STAGE_TILE(0, 0);
    STAGE_TILE(64, 1);

    for (int t = 0; t < 8; ++t) {
        const int s = t & 1;
        if (t < 7) {
            asm volatile("s_waitcnt vmcnt(8)" ::: "memory");
        } else {
            asm volatile("s_waitcnt vmcnt(0)" ::: "memory");
        }
        __builtin_amdgcn_s_barrier();   // whole tile t now valid in slot s

        const _Float16* As = &smem[s][0][0][0];
        const _Float16* Bs = &smem[s][1][0][0];

        f16x8 a0[8], a1[8], b0[4], b1[4];
#pragma unroll
        for (int fr = 0; fr < 8; ++fr) {
            const int rb = (wm2 + fr * 16 + m) * 64;
            a0[fr] = *(const f16x8*)&As[rb + c0k];
            a1[fr] = *(const f16x8*)&As[rb + c1k];
        }
#pragma unroll
        for (int fc = 0; fc < 4; ++fc) {
            const int rb = (wn4 + fc * 16 + m) * 64;
            b0[fc] = *(const f16x8*)&Bs[rb + c0k];
            b1[fc] = *(const f16x8*)&Bs[rb + c1k];
        }
        asm volatile("s_waitcnt lgkmcnt(0)" ::: "memory");
        __builtin_amdgcn_s_barrier();   // slot s free: all waves done reading

        if (t + 2 < 8) {
            const int k0n = (t + 2) * 64;
            STAGE_TILE(k0n, s);         // prefetch tile t+2 into freed slot
        }

        __builtin_amdgcn_s_setprio(1);
#pragma unroll
        for (int fr = 0; fr < 8; ++fr)
#pragma unroll
            for (int fc = 0; fc < 4; ++fc)
                acc[fr][fc] = __builtin_amdgcn_mfma_f32_16x16x32_f16(a0[fr], b0[fc], acc[fr][fc], 0, 0, 0);
#pragma unroll
        for (int fr = 0; fr < 8; ++fr)
#pragma unroll
            for (int fc = 0; fc < 4; ++fc)
                acc[fr][fc] = __builtin_amdgcn_mfma_f32_16x16x32_f16(a1[fr], b1[fc], acc[fr][fc], 0, 0, 0);
        __builtin_amdgcn_s_setprio(0);
    }
#undef STAGE_TILE

    // C/D layout: col = lane&15, row = (lane>>4)*4 + reg
#pragma unroll
    for (int fr = 0; fr < 8; ++fr) {
        const int rbase = row0 + wm2 + fr * 16 + q * 4;
#pragma unroll
        for (int fc = 0; fc < 4; ++fc) {
            const int col = col0 + wn4 + fc * 16 + m;
            const float bv = bias[col];
#pragma unroll
            for (int r = 0; r < 4; ++r)
                C[(size_t)(rbase + r) * ldc + col] = (_Float16)(acc[fr][fc][r] + bv);
        }
    }
}

// ---------------------------------------------------------------------------
// fp32 -> fp16 elementwise (vectorized x4)
// ---------------------------------------------------------------------------
__global__ __launch_bounds__(256)
void conv32to16(const float* __restrict__ in, _Float16* __restrict__ out, int n4) {
    int i = blockIdx.x * 256 + threadIdx.x;
    if (i < n4) {
        f32x4 v = ((const f32x4*)in)[i];
        f16x4 o = {(_Float16)v[0], (_Float16)v[1], (_Float16)v[2], (_Float16)v[3]};
        ((f16x4*)out)[i] = o;
    }
}

// ---------------------------------------------------------------------------
// Batched weight transpose fp32->fp16: z 0..2: W1[l]->W1allT; z 3..5:
// Wk,Wv,Wq -> WkvqT rows 0/512/1024.
// ---------------------------------------------------------------------------
__global__ __launch_bounds__(256)
void transpose_all(const float* __restrict__ W1, const float* __restrict__ Wk,
                   const float* __restrict__ Wv, const float* __restrict__ Wq,
                   _Float16* __restrict__ W1allT, _Float16* __restrict__ WkvqT) {
    const int z = blockIdx.z;
    const float* src;
    _Float16* dst;
    const size_t MSZ = (size_t)E_DIM * E_DIM;
    if (z < 3)       { src = W1 + z * MSZ; dst = W1allT + z * MSZ; }
    else if (z == 3) { src = Wk;           dst = WkvqT; }
    else if (z == 4) { src = Wv;           dst = WkvqT + MSZ; }
    else             { src = Wq;           dst = WkvqT + 2 * MSZ; }

    __shared__ float t[32][33];
    const int k0 = blockIdx.x * 32, n0 = blockIdx.y * 32;
    const int tx = threadIdx.x & 31, ty = threadIdx.x >> 5;
#pragma unroll
    for (int r = 0; r < 32; r += 8)
        t[ty + r][tx] = src[(size_t)(k0 + ty + r) * E_DIM + n0 + tx];
    __syncthreads();
#pragma unroll
    for (int r = 0; r < 32; r += 8)
        dst[(size_t)(n0 + ty + r) * E_DIM + k0 + tx] = (_Float16)t[tx][ty + r];
}

// ---------------------------------------------------------------------------
// Composed biases: bcomp[l][n] for n<512: b2_l@Wk + bk; [512,1024): Wv/bv;
// [1024,1536): Wq/bq.
// ---------------------------------------------------------------------------
__global__ __launch_bounds__(256)
void bias_compose(const float* __restrict__ b2, const float* __restrict__ Wk,
                  const float* __restrict__ Wv, const float* __restrict__ Wq,
                  const float* __restrict__ bk, const float* __restrict__ bv,
                  const float* __restrict__ bq, float* __restrict__ bcomp) {
    const int l = blockIdx.y;
    const int n = blockIdx.x * 256 + threadIdx.x;   // 0..1535
    const float* W; const float* bb; int nn;
    if (n < 512)       { W = Wk; bb = bk; nn = n; }
    else if (n < 1024) { W = Wv; bb = bv; nn = n - 512; }
    else               { W = Wq; bb = bq; nn = n - 1024; }
    float acc = 0.f;
    for (int j = 0; j < E_DIM; ++j)
        acc = fmaf(b2[l * E_DIM + j], W[(size_t)j * E_DIM + nn], acc);
    bcomp[l * 1536 + n] = acc + bb[nn];
}

// ---------------------------------------------------------------------------
// LayerNorm + ReLU over bufPall [N x 1536], all 3 levels in one dispatch.
// ---------------------------------------------------------------------------
__global__ __launch_bounds__(256)
void ln_relu_all(_Float16* __restrict__ P, const float* __restrict__ gamma,
                 const float* __restrict__ beta) {
    const int row = blockIdx.x * 4 + (threadIdx.x >> 6);
    const int l = blockIdx.y;
    const int lane = threadIdx.x & 63;
    _Float16* prow = P + (size_t)row * (L_LEV * E_DIM) + l * E_DIM + lane * 8;
    const float* g = gamma + l * E_DIM + lane * 8;
    const float* b = beta  + l * E_DIM + lane * 8;
    f16x8 v = *(const f16x8*)prow;
    float x[8];
    float s = 0.f, s2 = 0.f;
#pragma unroll
    for (int e = 0; e < 8; ++e) {
        x[e] = (float)v[e];
        s += x[e];
        s2 = fmaf(x[e], x[e], s2);
    }
#pragma unroll
    for (int off = 32; off; off >>= 1) {
        s  += __shfl_xor(s, off);
        s2 += __shfl_xor(s2, off);
    }
    const float mean = s * (1.f / E_DIM);
    const float var  = s2 * (1.f / E_DIM) - mean * mean;
    const float rstd = rsqrtf(var + LN_EPS);
    f32x4 g0 = *(const f32x4*)g;
    f32x4 g1 = *(const f32x4*)(g + 4);
    f32x4 b0 = *(const f32x4*)b;
    f32x4 b1 = *(const f32x4*)(b + 4);
    f16x8 o;
#pragma unroll
    for (int e = 0; e < 4; ++e) {
        o[e]     = (_Float16)fmaxf(fmaf((x[e]     - mean) * rstd, g0[e], b0[e]), 0.f);
        o[e + 4] = (_Float16)fmaxf(fmaf((x[e + 4] - mean) * rstd, g1[e], b1[e]), 0.f);
    }
    *(f16x8*)prow = o;
}

// ---------------------------------------------------------------------------
// Contention-free counting sort
// ---------------------------------------------------------------------------
__global__ __launch_bounds__(256)
void label_block_hist(const int* __restrict__ labels, int* __restrict__ blockCounts) {
    __shared__ int h[C_CLS];
    const int tid = threadIdx.x;
    if (tid < C_CLS) h[tid] = 0;
    __syncthreads();
    atomicAdd(&h[labels[blockIdx.x * 256 + tid]], 1);
    __syncthreads();
    if (tid < C_CLS) blockCounts[blockIdx.x * C_CLS + tid] = h[tid];
}

__global__ __launch_bounds__(64)
void scan_offsets(const int* __restrict__ blockCounts, int* __restrict__ counts,
                  int* __restrict__ offs, int* __restrict__ blockOffs) {
    const int c = threadIdx.x;
    int total = 0;
    for (int b = 0; b < SCAT_BLOCKS; ++b) total += blockCounts[b * C_CLS + c];
    counts[c] = total;
    __shared__ int tot[C_CLS];
    tot[c] = total;
    __syncthreads();
    int off = 0;
    for (int cc = 0; cc < c; ++cc) off += tot[cc];
    offs[c] = off;
    if (c == C_CLS - 1) offs[C_CLS] = off + total;
    int run = off;
    for (int b = 0; b < SCAT_BLOCKS; ++b) {
        blockOffs[b * C_CLS + c] = run;
        run += blockCounts[b * C_CLS + c];
    }
}

__global__ __launch_bounds__(256)
void scatter_sorted(const int* __restrict__ labels, const int* __restrict__ blockOffs,
                    int* __restrict__ members) {
    __shared__ int cur[C_CLS];
    const int tid = threadIdx.x;
    if (tid < C_CLS) cur[tid] = blockOffs[blockIdx.x * C_CLS + tid];
    __syncthreads();
    const int i = blockIdx.x * 256 + tid;
    const int c = labels[i];
    const int p = atomicAdd(&cur[c], 1);
    members[p] = i;
}

__global__ __launch_bounds__(256)
void zero_f32(float* __restrict__ p, int n) {
    int i = blockIdx.x * 256 + threadIdx.x;
    if (i < n) p[i] = 0.f;
}

// ---------------------------------------------------------------------------
// hpart[l][c][split][:] = partial segment-sum of h_l over class members.
// Batched over levels (grid.z); write-based (no atomics, no zero pass).
// ---------------------------------------------------------------------------
__global__ __launch_bounds__(256)
void ctx_partial(const _Float16* __restrict__ P, const int* __restrict__ members,
                 const int* __restrict__ offsets, float* __restrict__ hpart) {
    const int c = blockIdx.x, split = blockIdx.y, l = blockIdx.z;
    const _Float16* src = P + (size_t)l * E_DIM;
    const int tid = threadIdx.x;
    const int wave = tid >> 6, lane = tid & 63;
    const int start = offsets[c], end = offsets[c + 1];
    const int wg = split * 4 + wave;
    const int stride = 4 * CTX_SPLITS;
    const int ld = L_LEV * E_DIM;

    float acc[8];
#pragma unroll
    for (int e = 0; e < 8; ++e) acc[e] = 0.f;

    int i = start + wg;
    for (; i + stride < end; i += 2 * stride) {
        const int n0 = members[i];
        const int n1 = members[i + stride];
        f16x8 r0 = *(const f16x8*)(src + (size_t)n0 * ld + lane * 8);
        f16x8 r1 = *(const f16x8*)(src + (size_t)n1 * ld + lane * 8);
#pragma unroll
        for (int e = 0; e < 8; ++e) acc[e] += (float)r0[e] + (float)r1[e];
    }
    if (i < end) {
        const int n0 = members[i];
        f16x8 r0 = *(const f16x8*)(src + (size_t)n0 * ld + lane * 8);
#pragma unroll
        for (int e = 0; e < 8; ++e) acc[e] += (float)r0[e];
    }

    __shared__ float red[4][64][8];
#pragma unroll
    for (int e = 0; e < 8; ++e) red[wave][lane][e] = acc[e];
    __syncthreads();
    float* dst = hpart + (((size_t)l * C_CLS + c) * CTX_SPLITS + split) * E_DIM;
#pragma unroll
    for (int t = 0; t < 2; ++t) {
        const int col = tid * 2 + t;
        const int ln = col >> 3, e = col & 7;
        dst[col] = red[0][ln][e] + red[1][ln][e] + red[2][ln][e] + red[3][ln][e];
    }
}

// ---------------------------------------------------------------------------
// q[l][c][:] = (mean of h_l over class c) @ (W2_l@Wq) + composed bias.
// Batched over levels (grid.y). Reduces the CTX_SPLITS partials inline.
// ---------------------------------------------------------------------------
__global__ __launch_bounds__(256)
void row_gemm_q(const float* __restrict__ hpart, const int* __restrict__ counts,
                const _Float16* __restrict__ W2compT, const float* __restrict__ bcomp,
                float* __restrict__ q) {
    const int c = blockIdx.x, l = blockIdx.y;
    const int tid = threadIdx.x;
    const float inv = 1.f / (float)counts[c];
    __shared__ float xrow[E_DIM];
    const float* hp = hpart + ((size_t)l * C_CLS + c) * CTX_SPLITS * E_DIM;
    float s0 = 0.f, s1 = 0.f;
#pragma unroll
    for (int s = 0; s < CTX_SPLITS; ++s) {
        s0 += hp[s * E_DIM + tid];
        s1 += hp[s * E_DIM + tid + 256];
    }
    xrow[tid]       = s0 * inv;
    xrow[tid + 256] = s1 * inv;
    __syncthreads();

    const _Float16* Wq = W2compT + (size_t)l * 1536 * E_DIM + (size_t)1024 * E_DIM;
    const float* bias = bcomp + l * 1536 + 1024;
    const int n0 = tid, n1 = tid + 256;
    float a0 = 0.f, a1 = 0.f;
#pragma unroll 4
    for (int k0 = 0; k0 < E_DIM; k0 += 8) {
        f16x8 w0 = *(const f16x8*)(Wq + (size_t)n0 * E_DIM + k0);
        f16x8 w1 = *(const f16x8*)(Wq + (size_t)n1 * E_DIM + k0);
#pragma unroll
        for (int e = 0; e < 8; ++e) {
            const float xv = xrow[k0 + e];
            a0 = fmaf(xv, (float)w0[e], a0);
            a1 = fmaf(xv, (float)w1[e], a1);
        }
    }
    float* qq = q + (size_t)l * C_CLS * E_DIM;
    qq[c * E_DIM + n0] = a0 + bias[n0];
    qq[c * E_DIM + n1] = a1 + bias[n1];
}

// ---------------------------------------------------------------------------
// Segment attention, phase 1. K/V packed: row n = [K(512) | V(512)] in bufKV.
// grid (C, H, ATTN_SPLITS). NOTE: splits/waves beyond the member count are
// legitimately empty (m=-inf); the combine must guard exp(-inf - -inf).
// ---------------------------------------------------------------------------
__global__ __launch_bounds__(256)
void attn_partial(const float* __restrict__ q, const _Float16* __restrict__ kv,
                  const int* __restrict__ members, const int* __restrict__ offsets,
                  float* __restrict__ pm, float* __restrict__ pl,
                  float* __restrict__ po) {
    const int c = blockIdx.x, h = blockIdx.y, s = blockIdx.z;
    const int tid = threadIdx.x;
    const int wave = tid >> 6, lane = tid & 63;
    const int start = offsets[c], end = offsets[c + 1];
    const int g = s * 4 + wave;                 // 0..4*SPLITS-1

    float qv[64];
    const bool active = (start + g * 64) < end;
    if (active) {
        const float* qrow = q + c * E_DIM + h * DHD;
#pragma unroll
        for (int d = 0; d < 64; ++d) qv[d] = qrow[d];
    }

    __shared__ float ps[4][64];
    float m = -INFINITY, lsum = 0.f, out = 0.f; // lane owns output dim `lane`

    for (int ch0 = start + g * 64; ch0 < end; ch0 += 4 * ATTN_SPLITS * 64) {
        const int nvalid = min(64, end - ch0);
        const int idx = ch0 + lane;
        const int mi = members[idx < end ? idx : end - 1];
        const _Float16* krow = kv + (size_t)mi * KV_LD + h * DHD;
        float dot = 0.f;
#pragma unroll
        for (int j = 0; j < 8; ++j) {
            f16x8 kr = *(const f16x8*)(krow + j * 8);
#pragma unroll
            for (int e = 0; e < 8; ++e)
                dot = fmaf((float)kr[e], qv[j * 8 + e], dot);
        }
        float sc = (lane < nvalid) ? dot * 0.125f : -INFINITY;
        float cm = sc;
#pragma unroll
        for (int off = 32; off; off >>= 1) cm = fmaxf(cm, __shfl_xor(cm, off));
        const float nm = fmaxf(m, cm);
        const float alpha = __expf(m - nm);
        const float p = (lane < nvalid) ? __expf(sc - nm) : 0.f;
        ps[wave][lane] = p;
        out *= alpha;
        lsum *= alpha;
        m = nm;
        asm volatile("" ::: "memory");
#pragma unroll 16
        for (int j = 0; j < 64; ++j) {
            const int nj = __shfl(mi, j);
            const float pj = ps[wave][j];
            const float vv = (float)kv[(size_t)nj * KV_LD + E_DIM + h * DHD + lane];
            out = fmaf(pj, vv, out);
            lsum += pj;
        }
    }

    __shared__ float rm[4], rl[4], racc[4][64];
    racc[wave][lane] = out;
    if (lane == 0) { rm[wave] = m; rl[wave] = lsum; }
    __syncthreads();
    if (wave == 0) {
        float M = fmaxf(fmaxf(rm[0], rm[1]), fmaxf(rm[2], rm[3]));
        float o = 0.f, Lt = 0.f;
#pragma unroll
        for (int w = 0; w < 4; ++w) {
            // guard: rm[w]==-inf (empty wave) AND possibly M==-inf (all empty)
            // -> exp(-inf - -inf) = NaN without the guard. [R10 NaN bug]
            const float al = (rm[w] > -INFINITY) ? __expf(rm[w] - M) : 0.f;
            o  += al * racc[w][lane];
            Lt += al * rl[w];
        }
        const int pidx = (c * H_HEADS + h) * ATTN_SPLITS + s;
        po[pidx * 64 + lane] = o;      // 0 for all-empty block
        if (lane == 0) { pm[pidx] = M; pl[pidx] = Lt; }
    }
}

// ---------------------------------------------------------------------------
// Combine ATTN_SPLITS partials for all 8 heads of class c into LDS xrow,
// then proto = xrow @ Wo + bo; out (+)= coef_l * proto.
// ---------------------------------------------------------------------------
__global__ __launch_bounds__(256)
void proto_accum(const float* __restrict__ pm, const float* __restrict__ pl,
                 const float* __restrict__ po, const float* __restrict__ Wo,
                 const float* __restrict__ bo, const float* __restrict__ lvlw,
                 const float* __restrict__ lvlt, int l, float* __restrict__ out) {
    const int c = blockIdx.x;
    const int tid = threadIdx.x;
    const int wave = tid >> 6, lane = tid & 63;
    __shared__ float xrow[E_DIM];
#pragma unroll
    for (int hh = wave; hh < H_HEADS; hh += 4) {
        const int ch = c * H_HEADS + hh;
        float M = -INFINITY;
#pragma unroll
        for (int s = 0; s < ATTN_SPLITS; ++s) M = fmaxf(M, pm[ch * ATTN_SPLITS + s]);
        float o = 0.f, Lt = 0.f;
#pragma unroll
        for (int s = 0; s < ATTN_SPLITS; ++s) {
            const int pidx = ch * ATTN_SPLITS + s;
            // guard empty split: pm=-inf -> weight 0 (avoids 0*NaN / exp NaN)
            const float al = (pm[pidx] > -INFINITY) ? __expf(pm[pidx] - M) : 0.f;
            o  += al * po[pidx * 64 + lane];
            Lt += al * pl[pidx];
        }
        xrow[hh * 64 + lane] = o / Lt;
    }
    __syncthreads();

    float a0 = 0.f, a1 = 0.f;
#pragma unroll 8
    for (int k = 0; k < E_DIM; ++k) {
        float cv = xrow[k];
        a0 = fmaf(cv, Wo[(size_t)k * E_DIM + tid], a0);
        a1 = fmaf(cv, Wo[(size_t)k * E_DIM + tid + 256], a1);
    }
    float w0 = lvlw[0], w1 = lvlw[1], w2 = lvlw[2];
    float mx = fmaxf(w0, fmaxf(w1, w2));
    float e0 = expf(w0 - mx), e1 = expf(w1 - mx), e2 = expf(w2 - mx);
    float ssum = e0 + e1 + e2;
    float lw = (l == 0 ? e0 : (l == 1 ? e1 : e2)) / ssum;
    float coef = lw / lvlt[l];
    float r0 = (a0 + bo[tid]) * coef;
    float r1 = (a1 + bo[tid + 256]) * coef;
    if (l == 0) {
        out[c * E_DIM + tid]       = r0;
        out[c * E_DIM + tid + 256] = r1;
    } else {
        out[c * E_DIM + tid]       += r0;
        out[c * E_DIM + tid + 256] += r1;
    }
}

// ---------------------------------------------------------------------------
extern "C" void kernel_launch(void* const* d_in, const int* in_sizes, int n_in,
                              void* d_out, int out_size, void* d_ws, size_t ws_size,
                              hipStream_t stream) {
    const float* X      = (const float*)d_in[0];
    const int*   labels = (const int*)  d_in[1];
    const float* W1     = (const float*)d_in[2];
    const float* b1     = (const float*)d_in[3];   // [3,512] flat == fused bias
    const float* gamma  = (const float*)d_in[4];
    const float* beta   = (const float*)d_in[5];
    const float* W2     = (const float*)d_in[6];
    const float* b2     = (const float*)d_in[7];
    const float* Wq     = (const float*)d_in[8];
    const float* bq     = (const float*)d_in[9];
    const float* Wk     = (const float*)d_in[10];
    const float* bk     = (const float*)d_in[11];
    const float* Wv     = (const float*)d_in[12];
    const float* bv     = (const float*)d_in[13];
    const float* Wo     = (const float*)d_in[14];
    const float* bo     = (const float*)d_in[15];
    const float* lvlw   = (const float*)d_in[16];
    const float* lvlt   = (const float*)d_in[17];
    float* out = (float*)d_out;

    // Workspace carve (~401 MB of the 512 MiB ws)
    char* p = (char*)d_ws;
    const size_t MSZ = (size_t)E_DIM * E_DIM;                       // 262144
    _Float16* Xh      = (_Float16*)p; p += (size_t)N_SUP * E_DIM * 2;         // 64 MB
    _Float16* bufPall = (_Float16*)p; p += (size_t)N_SUP * E_DIM * L_LEV * 2; // 192 MB
    _Float16* bufKV   = (_Float16*)p; p += (size_t)N_SUP * KV_LD * 2;         // 128 MB
    _Float16* W1allT  = (_Float16*)p; p += L_LEV * MSZ * 2;
    _Float16* WkvqT   = (_Float16*)p; p += 3 * MSZ * 2;
    _Float16* W2f16   = (_Float16*)p; p += L_LEV * MSZ * 2;
    _Float16* W2compT = (_Float16*)p; p += (size_t)L_LEV * 1536 * E_DIM * 2;
    float* zeros512 = (float*)p; p += E_DIM * sizeof(float);
    float* bcomp = (float*)p; p += L_LEV * 1536 * sizeof(float);
    float* hpart = (float*)p; p += (size_t)L_LEV * C_CLS * CTX_SPLITS * E_DIM * sizeof(float); // 6 MB
    float* qb    = (float*)p; p += (size_t)L_LEV * C_CLS * E_DIM * sizeof(float);
    float* pm    = (float*)p; p += C_CLS * H_HEADS * ATTN_SPLITS * sizeof(float);
    float* pl    = (float*)p; p += C_CLS * H_HEADS * ATTN_SPLITS * sizeof(float);
    float* po    = (float*)p; p += (size_t)C_CLS * H_HEADS * ATTN_SPLITS * 64 * sizeof(float);
    int* counts      = (int*)p; p += 256;
    int* offs        = (int*)p; p += 512;
    int* members     = (int*)p; p += (size_t)N_SUP * sizeof(int);
    int* blockCounts = (int*)p; p += (size_t)SCAT_BLOCKS * C_CLS * sizeof(int);
    int* blockOffs   = (int*)p; p += (size_t)SCAT_BLOCKS * C_CLS * sizeof(int);

    // Class membership: contention-free counting sort
    label_block_hist<<<SCAT_BLOCKS, 256, 0, stream>>>(labels, blockCounts);
    scan_offsets<<<1, 64, 0, stream>>>(blockCounts, counts, offs, blockOffs);
    scatter_sorted<<<SCAT_BLOCKS, 256, 0, stream>>>(labels, blockOffs, members);

    // Conversions / transposes
    conv32to16<<<(N_SUP * E_DIM / 4) / 256, 256, 0, stream>>>(X, Xh, N_SUP * E_DIM / 4);
    conv32to16<<<(int)(L_LEV * MSZ / 4 / 256), 256, 0, stream>>>(W2, W2f16, L_LEV * MSZ / 4);
    transpose_all<<<dim3(16, 16, 6), 256, 0, stream>>>(W1, Wk, Wv, Wq, W1allT, WkvqT);
    zero_f32<<<2, 256, 0, stream>>>(zeros512, E_DIM);

    // Composed weights: W2compT_l = [WkT;WvT;WqT] @ W2T_l  (fp16 MFMA, batched)
    // M=1536 (6 row-tiles), N=512 (2 col-tiles)
    hgemm256<<<dim3(6 * 2, L_LEV), 512, 0, stream>>>(
        WkvqT, E_DIM, 0, W2f16, MSZ, zeros512, 0,
        W2compT, E_DIM, (size_t)1536 * E_DIM, 2);
    bias_compose<<<dim3(6, L_LEV), 256, 0, stream>>>(b2, Wk, Wv, Wq, bk, bv, bq, bcomp);

    const int nRowT = N_SUP / 256;   // 256 row tiles
    // Fused pre = X @ [W1_0|W1_1|W1_2] + b1  -> bufPall [N x 1536]
    hgemm256<<<dim3(nRowT * 6, 1), 512, 0, stream>>>(
        Xh, E_DIM, 0, W1allT, 0, b1, 0, bufPall, L_LEV * E_DIM, 0, 6);
    // LN+ReLU for all 3 levels (bufPall now holds h)
    ln_relu_all<<<dim3(N_SUP / 4, L_LEV), 256, 0, stream>>>(bufPall, gamma, beta);

    // Level-independent tail, batched once: segment-sum partials + q
    ctx_partial<<<dim3(C_CLS, CTX_SPLITS, L_LEV), 256, 0, stream>>>(
        bufPall, members, offs, hpart);
    row_gemm_q<<<dim3(C_CLS, L_LEV), 256, 0, stream>>>(
        hpart, counts, W2compT, bcomp, qb);

    for (int l = 0; l < L_LEV; ++l) {
        // [K|V] = h_l @ (W2_l@[Wk|Wv]) + composed bias  -> bufKV [N x 1024]
        hgemm256<<<dim3(nRowT * 4, 1), 512, 0, stream>>>(
            bufPall + (size_t)l * E_DIM, L_LEV * E_DIM, 0,
            W2compT + (size_t)l * 1536 * E_DIM, 0,
            bcomp + l * 1536, 0, bufKV, KV_LD, 0, 4);
        attn_partial<<<dim3(C_CLS, H_HEADS, ATTN_SPLITS), 256, 0, stream>>>(
            qb + (size_t)l * C_CLS * E_DIM, bufKV, members, offs, pm, pl, po);
        proto_accum<<<C_CLS, 256, 0, stream>>>(pm, pl, po, Wo, bo, lvlw, lvlt, l, out);
    }
}

// Round 3
// 1032.334 us; speedup vs baseline: 1.0058x; 1.0058x over previous
//
#include <hip/hip_runtime.h>
#include <math.h>

// Problem constants (fixed by the reference)
#define N_SUP 65536
#define E_DIM 512
#define H_HEADS 8
#define C_CLS 64
#define DHD 64
#define L_LEV 3
#define LN_EPS 1e-5f
#define ATTN_SPLITS 8
#define CTX_SPLITS 16
#define SCAT_BLOCKS 256        // N_SUP / 256
#define KV_LD 1024

typedef _Float16 f16x8 __attribute__((ext_vector_type(8)));
typedef _Float16 f16x4 __attribute__((ext_vector_type(4)));
typedef float f32x4 __attribute__((ext_vector_type(4)));

// ---------------------------------------------------------------------------
// async global->LDS copy, 16B per lane (wave-uniform LDS base + lane*16;
// global source address is per-lane).
// ---------------------------------------------------------------------------
__device__ __forceinline__ void gload_lds16(const void* g, void* lds) {
    __builtin_amdgcn_global_load_lds((const __attribute__((address_space(1))) void*)g,
                                     (__attribute__((address_space(3))) void*)lds,
                                     16, 0, 0);
}

// ---------------------------------------------------------------------------
// fp16 GEMM, 256x256 tile, BK=64, 8 waves (2M x 4N), counted-vmcnt pipeline.
//   C[M x Ncols] = A[M x 512] @ B + bias; Bt is B^T [Ncols x 512].
// K fixed at 512 -> 8 K-tiles of 64. Two LDS slots; slot t&1 holds tile t.
// Per tile t:
//   vmcnt(8) [tile t's 8 loads done; tile t+1's 8 may be in flight] -> barrier
//   -> {24x ds_read_b128 + 64x MFMA} as ONE compiler-scheduled region
//      (fine-grained lgkmcnt interleave: LDS service hides under MFMA issue;
//       NO forced lgkmcnt(0), NO mid-tile barrier -- that serialization was
//       the R2 regression: MfmaUtil 28%, both pipes taking turns)
//   -> fence + barrier [slot free: MFMA done => reads done]
//   -> stage tile t+2 into the freed slot (full iteration of latency cover).
// Swizzle: LDS(row r, 16B-block b) holds global k-block (b ^ (r&7)); read side
// uses blk = (4*kk + q) ^ (m&7) with r&7 == m&7 -> involution cancels ->
// conflict-free (SQ_LDS_BANK_CONFLICT measured 0).
// Band swizzle on grid.x preserved for A-panel L2 reuse.
// ---------------------------------------------------------------------------
__global__ __launch_bounds__(512, 2)
void hgemm256(const _Float16* __restrict__ A, int lda, size_t aStride,
              const _Float16* __restrict__ Bt, size_t btStride,
              const float* __restrict__ bias, size_t biasStride,
              _Float16* __restrict__ C, int ldc, size_t cStride, int nCol) {
    const int z = blockIdx.y;
    A += z * aStride; Bt += z * btStride; bias += z * biasStride; C += z * cStride;

    const int nRow = gridDim.x / nCol;
    const int R = nRow < 64 ? nRow : 64;
    const int bid = blockIdx.x;
    const int bandSz = R * nCol;
    const int band = bid / bandSz;
    const int rem = bid % bandSz;
    const int colT = rem / R;
    const int rowT = band * R + (rem % R);
    const int row0 = rowT * 256, col0 = colT * 256;

    // [slot][A/B][256 rows][64 f16] = 128 KiB
    __shared__ _Float16 smem[2][2][256][64];

    const int tid = threadIdx.x;
    const int wave = tid >> 6, lane = tid & 63;
    const int wm2 = (wave & 1) * 128;     // M half of this wave
    const int wn4 = (wave >> 1) * 64;     // N quarter of this wave
    const int m = lane & 15, q = lane >> 4;

    // staging: thread -> (row sr in 0..63 per pass, 16B-block sb), swizzled src
    const int sr = tid >> 3;
    const int sb = tid & 7;
    const int sblk = sb ^ (sr & 7);       // r&7 == sr&7 for every pass (p*64)

    const _Float16* Asrc = A + (size_t)(row0 + sr) * lda + sblk * 8;
    const _Float16* Bsrc = Bt + (size_t)(col0 + sr) * E_DIM + sblk * 8;
    const size_t aPass = (size_t)64 * lda;   // 64 rows per pass
    const size_t bPass = (size_t)64 * E_DIM;

#define STAGE_TILE(k0, s)                                                     \
    {                                                                         \
        char* la = (char*)&smem[s][0][0][0] + wave * 1024;                    \
        char* lb = (char*)&smem[s][1][0][0] + wave * 1024;                    \
        _Pragma("unroll")                                                     \
        for (int p = 0; p < 4; ++p)                                           \
            gload_lds16(Asrc + (size_t)p * aPass + (k0), la + p * 8192);      \
        _Pragma("unroll")                                                     \
        for (int p = 0; p < 4; ++p)                                           \
            gload_lds16(Bsrc + (size_t)p * bPass + (k0), lb + p * 8192);      \
    }

    f32x4 acc[8][4];
#pragma unroll
    for (int i = 0; i < 8; ++i)
#pragma unroll
        for (int j = 0; j < 4; ++j) acc[i][j] = (f32x4){0.f, 0.f, 0.f, 0.f};

    // element offsets of the two kk sub-steps (in f16), swizzled
    const int c0k = ((q) ^ (m & 7)) * 8;
    const int c1k = ((4 + q) ^ (m & 7)) * 8;

    // prologue: stage tiles 0 and 1 (8 loads each per thread)
    STAGE_TILE(0, 0);
    STAGE_TILE(64, 1);

    for (int t = 0; t < 8; ++t) {
        const int s = t & 1;
        if (t < 7) {
            asm volatile("s_waitcnt vmcnt(8)" ::: "memory");
        } else {
            asm volatile("s_waitcnt vmcnt(0)" ::: "memory");
        }
        __builtin_amdgcn_s_barrier();   // whole tile t now valid in slot s

        const _Float16* As = &smem[s][0][0][0];
        const _Float16* Bs = &smem[s][1][0][0];

        // One region: compiler interleaves ds_read_b128 with MFMA via
        // fine-grained lgkmcnt — LDS service hides under MFMA issue.
        f16x8 a0[8], a1[8], b0[4], b1[4];
#pragma unroll
        for (int fr = 0; fr < 8; ++fr) {
            const int rb = (wm2 + fr * 16 + m) * 64;
            a0[fr] = *(const f16x8*)&As[rb + c0k];
            a1[fr] = *(const f16x8*)&As[rb + c1k];
        }
#pragma unroll
        for (int fc = 0; fc < 4; ++fc) {
            const int rb = (wn4 + fc * 16 + m) * 64;
            b0[fc] = *(const f16x8*)&Bs[rb + c0k];
            b1[fc] = *(const f16x8*)&Bs[rb + c1k];
        }
        __builtin_amdgcn_s_setprio(1);
#pragma unroll
        for (int fr = 0; fr < 8; ++fr)
#pragma unroll
            for (int fc = 0; fc < 4; ++fc)
                acc[fr][fc] = __builtin_amdgcn_mfma_f32_16x16x32_f16(a0[fr], b0[fc], acc[fr][fc], 0, 0, 0);
#pragma unroll
        for (int fr = 0; fr < 8; ++fr)
#pragma unroll
            for (int fc = 0; fc < 4; ++fc)
                acc[fr][fc] = __builtin_amdgcn_mfma_f32_16x16x32_f16(a1[fr], b1[fc], acc[fr][fc], 0, 0, 0);
        __builtin_amdgcn_s_setprio(0);

        asm volatile("" ::: "memory");   // no LDS reads sink past this point
        __builtin_amdgcn_s_barrier();    // slot s free: all waves done reading

        if (t + 2 < 8) {
            const int k0n = (t + 2) * 64;
            STAGE_TILE(k0n, s);          // prefetch tile t+2 into freed slot
        }
    }
#undef STAGE_TILE

    // C/D layout: col = lane&15, row = (lane>>4)*4 + reg
#pragma unroll
    for (int fr = 0; fr < 8; ++fr) {
        const int rbase = row0 + wm2 + fr * 16 + q * 4;
#pragma unroll
        for (int fc = 0; fc < 4; ++fc) {
            const int col = col0 + wn4 + fc * 16 + m;
            const float bv = bias[col];
#pragma unroll
            for (int r = 0; r < 4; ++r)
                C[(size_t)(rbase + r) * ldc + col] = (_Float16)(acc[fr][fc][r] + bv);
        }
    }
}

// ---------------------------------------------------------------------------
// fp32 -> fp16 elementwise (vectorized x4)
// ---------------------------------------------------------------------------
__global__ __launch_bounds__(256)
void conv32to16(const float* __restrict__ in, _Float16* __restrict__ out, int n4) {
    int i = blockIdx.x * 256 + threadIdx.x;
    if (i < n4) {
        f32x4 v = ((const f32x4*)in)[i];
        f16x4 o = {(_Float16)v[0], (_Float16)v[1], (_Float16)v[2], (_Float16)v[3]};
        ((f16x4*)out)[i] = o;
    }
}

// ---------------------------------------------------------------------------
// Batched weight transpose fp32->fp16: z 0..2: W1[l]->W1allT; z 3..5:
// Wk,Wv,Wq -> WkvqT rows 0/512/1024.
// ---------------------------------------------------------------------------
__global__ __launch_bounds__(256)
void transpose_all(const float* __restrict__ W1, const float* __restrict__ Wk,
                   const float* __restrict__ Wv, const float* __restrict__ Wq,
                   _Float16* __restrict__ W1allT, _Float16* __restrict__ WkvqT) {
    const int z = blockIdx.z;
    const float* src;
    _Float16* dst;
    const size_t MSZ = (size_t)E_DIM * E_DIM;
    if (z < 3)       { src = W1 + z * MSZ; dst = W1allT + z * MSZ; }
    else if (z == 3) { src = Wk;           dst = WkvqT; }
    else if (z == 4) { src = Wv;           dst = WkvqT + MSZ; }
    else             { src = Wq;           dst = WkvqT + 2 * MSZ; }

    __shared__ float t[32][33];
    const int k0 = blockIdx.x * 32, n0 = blockIdx.y * 32;
    const int tx = threadIdx.x & 31, ty = threadIdx.x >> 5;
#pragma unroll
    for (int r = 0; r < 32; r += 8)
        t[ty + r][tx] = src[(size_t)(k0 + ty + r) * E_DIM + n0 + tx];
    __syncthreads();
#pragma unroll
    for (int r = 0; r < 32; r += 8)
        dst[(size_t)(n0 + ty + r) * E_DIM + k0 + tx] = (_Float16)t[tx][ty + r];
}

// ---------------------------------------------------------------------------
// Composed biases: bcomp[l][n] for n<512: b2_l@Wk + bk; [512,1024): Wv/bv;
// [1024,1536): Wq/bq.
// ---------------------------------------------------------------------------
__global__ __launch_bounds__(256)
void bias_compose(const float* __restrict__ b2, const float* __restrict__ Wk,
                  const float* __restrict__ Wv, const float* __restrict__ Wq,
                  const float* __restrict__ bk, const float* __restrict__ bv,
                  const float* __restrict__ bq, float* __restrict__ bcomp) {
    const int l = blockIdx.y;
    const int n = blockIdx.x * 256 + threadIdx.x;   // 0..1535
    const float* W; const float* bb; int nn;
    if (n < 512)       { W = Wk; bb = bk; nn = n; }
    else if (n < 1024) { W = Wv; bb = bv; nn = n - 512; }
    else               { W = Wq; bb = bq; nn = n - 1024; }
    float acc = 0.f;
    for (int j = 0; j < E_DIM; ++j)
        acc = fmaf(b2[l * E_DIM + j], W[(size_t)j * E_DIM + nn], acc);
    bcomp[l * 1536 + n] = acc + bb[nn];
}

// ---------------------------------------------------------------------------
// LayerNorm + ReLU over bufPall [N x 1536], all 3 levels in one dispatch.
// ---------------------------------------------------------------------------
__global__ __launch_bounds__(256)
void ln_relu_all(_Float16* __restrict__ P, const float* __restrict__ gamma,
                 const float* __restrict__ beta) {
    const int row = blockIdx.x * 4 + (threadIdx.x >> 6);
    const int l = blockIdx.y;
    const int lane = threadIdx.x & 63;
    _Float16* prow = P + (size_t)row * (L_LEV * E_DIM) + l * E_DIM + lane * 8;
    const float* g = gamma + l * E_DIM + lane * 8;
    const float* b = beta  + l * E_DIM + lane * 8;
    f16x8 v = *(const f16x8*)prow;
    float x[8];
    float s = 0.f, s2 = 0.f;
#pragma unroll
    for (int e = 0; e < 8; ++e) {
        x[e] = (float)v[e];
        s += x[e];
        s2 = fmaf(x[e], x[e], s2);
    }
#pragma unroll
    for (int off = 32; off; off >>= 1) {
        s  += __shfl_xor(s, off);
        s2 += __shfl_xor(s2, off);
    }
    const float mean = s * (1.f / E_DIM);
    const float var  = s2 * (1.f / E_DIM) - mean * mean;
    const float rstd = rsqrtf(var + LN_EPS);
    f32x4 g0 = *(const f32x4*)g;
    f32x4 g1 = *(const f32x4*)(g + 4);
    f32x4 b0 = *(const f32x4*)b;
    f32x4 b1 = *(const f32x4*)(b + 4);
    f16x8 o;
#pragma unroll
    for (int e = 0; e < 4; ++e) {
        o[e]     = (_Float16)fmaxf(fmaf((x[e]     - mean) * rstd, g0[e], b0[e]), 0.f);
        o[e + 4] = (_Float16)fmaxf(fmaf((x[e + 4] - mean) * rstd, g1[e], b1[e]), 0.f);
    }
    *(f16x8*)prow = o;
}

// ---------------------------------------------------------------------------
// Contention-free counting sort
// ---------------------------------------------------------------------------
__global__ __launch_bounds__(256)
void label_block_hist(const int* __restrict__ labels, int* __restrict__ blockCounts) {
    __shared__ int h[C_CLS];
    const int tid = threadIdx.x;
    if (tid < C_CLS) h[tid] = 0;
    __syncthreads();
    atomicAdd(&h[labels[blockIdx.x * 256 + tid]], 1);
    __syncthreads();
    if (tid < C_CLS) blockCounts[blockIdx.x * C_CLS + tid] = h[tid];
}

__global__ __launch_bounds__(64)
void scan_offsets(const int* __restrict__ blockCounts, int* __restrict__ counts,
                  int* __restrict__ offs, int* __restrict__ blockOffs) {
    const int c = threadIdx.x;
    int total = 0;
    for (int b = 0; b < SCAT_BLOCKS; ++b) total += blockCounts[b * C_CLS + c];
    counts[c] = total;
    __shared__ int tot[C_CLS];
    tot[c] = total;
    __syncthreads();
    int off = 0;
    for (int cc = 0; cc < c; ++cc) off += tot[cc];
    offs[c] = off;
    if (c == C_CLS - 1) offs[C_CLS] = off + total;
    int run = off;
    for (int b = 0; b < SCAT_BLOCKS; ++b) {
        blockOffs[b * C_CLS + c] = run;
        run += blockCounts[b * C_CLS + c];
    }
}

__global__ __launch_bounds__(256)
void scatter_sorted(const int* __restrict__ labels, const int* __restrict__ blockOffs,
                    int* __restrict__ members) {
    __shared__ int cur[C_CLS];
    const int tid = threadIdx.x;
    if (tid < C_CLS) cur[tid] = blockOffs[blockIdx.x * C_CLS + tid];
    __syncthreads();
    const int i = blockIdx.x * 256 + tid;
    const int c = labels[i];
    const int p = atomicAdd(&cur[c], 1);
    members[p] = i;
}

__global__ __launch_bounds__(256)
void zero_f32(float* __restrict__ p, int n) {
    int i = blockIdx.x * 256 + threadIdx.x;
    if (i < n) p[i] = 0.f;
}

// ---------------------------------------------------------------------------
// hpart[l][c][split][:] = partial segment-sum of h_l over class members.
// Batched over levels (grid.z); write-based (no atomics, no zero pass).
// ---------------------------------------------------------------------------
__global__ __launch_bounds__(256)
void ctx_partial(const _Float16* __restrict__ P, const int* __restrict__ members,
                 const int* __restrict__ offsets, float* __restrict__ hpart) {
    const int c = blockIdx.x, split = blockIdx.y, l = blockIdx.z;
    const _Float16* src = P + (size_t)l * E_DIM;
    const int tid = threadIdx.x;
    const int wave = tid >> 6, lane = tid & 63;
    const int start = offsets[c], end = offsets[c + 1];
    const int wg = split * 4 + wave;
    const int stride = 4 * CTX_SPLITS;
    const int ld = L_LEV * E_DIM;

    float acc[8];
#pragma unroll
    for (int e = 0; e < 8; ++e) acc[e] = 0.f;

    int i = start + wg;
    for (; i + stride < end; i += 2 * stride) {
        const int n0 = members[i];
        const int n1 = members[i + stride];
        f16x8 r0 = *(const f16x8*)(src + (size_t)n0 * ld + lane * 8);
        f16x8 r1 = *(const f16x8*)(src + (size_t)n1 * ld + lane * 8);
#pragma unroll
        for (int e = 0; e < 8; ++e) acc[e] += (float)r0[e] + (float)r1[e];
    }
    if (i < end) {
        const int n0 = members[i];
        f16x8 r0 = *(const f16x8*)(src + (size_t)n0 * ld + lane * 8);
#pragma unroll
        for (int e = 0; e < 8; ++e) acc[e] += (float)r0[e];
    }

    __shared__ float red[4][64][8];
#pragma unroll
    for (int e = 0; e < 8; ++e) red[wave][lane][e] = acc[e];
    __syncthreads();
    float* dst = hpart + (((size_t)l * C_CLS + c) * CTX_SPLITS + split) * E_DIM;
#pragma unroll
    for (int t = 0; t < 2; ++t) {
        const int col = tid * 2 + t;
        const int ln = col >> 3, e = col & 7;
        dst[col] = red[0][ln][e] + red[1][ln][e] + red[2][ln][e] + red[3][ln][e];
    }
}

// ---------------------------------------------------------------------------
// q[l][c][:] = (mean of h_l over class c) @ (W2_l@Wq) + composed bias.
// Batched over levels (grid.y). Reduces the CTX_SPLITS partials inline.
// ---------------------------------------------------------------------------
__global__ __launch_bounds__(256)
void row_gemm_q(const float* __restrict__ hpart, const int* __restrict__ counts,
                const _Float16* __restrict__ W2compT, const float* __restrict__ bcomp,
                float* __restrict__ q) {
    const int c = blockIdx.x, l = blockIdx.y;
    const int tid = threadIdx.x;
    const float inv = 1.f / (float)counts[c];
    __shared__ float xrow[E_DIM];
    const float* hp = hpart + ((size_t)l * C_CLS + c) * CTX_SPLITS * E_DIM;
    float s0 = 0.f, s1 = 0.f;
#pragma unroll
    for (int s = 0; s < CTX_SPLITS; ++s) {
        s0 += hp[s * E_DIM + tid];
        s1 += hp[s * E_DIM + tid + 256];
    }
    xrow[tid]       = s0 * inv;
    xrow[tid + 256] = s1 * inv;
    __syncthreads();

    const _Float16* Wq = W2compT + (size_t)l * 1536 * E_DIM + (size_t)1024 * E_DIM;
    const float* bias = bcomp + l * 1536 + 1024;
    const int n0 = tid, n1 = tid + 256;
    float a0 = 0.f, a1 = 0.f;
#pragma unroll 4
    for (int k0 = 0; k0 < E_DIM; k0 += 8) {
        f16x8 w0 = *(const f16x8*)(Wq + (size_t)n0 * E_DIM + k0);
        f16x8 w1 = *(const f16x8*)(Wq + (size_t)n1 * E_DIM + k0);
#pragma unroll
        for (int e = 0; e < 8; ++e) {
            const float xv = xrow[k0 + e];
            a0 = fmaf(xv, (float)w0[e], a0);
            a1 = fmaf(xv, (float)w1[e], a1);
        }
    }
    float* qq = q + (size_t)l * C_CLS * E_DIM;
    qq[c * E_DIM + n0] = a0 + bias[n0];
    qq[c * E_DIM + n1] = a1 + bias[n1];
}

// ---------------------------------------------------------------------------
// Segment attention, phase 1. K/V packed: row n = [K(512) | V(512)] in bufKV.
// grid (C, H, ATTN_SPLITS). NOTE: splits/waves beyond the member count are
// legitimately empty (m=-inf); the combine must guard exp(-inf - -inf).
// ---------------------------------------------------------------------------
__global__ __launch_bounds__(256)
void attn_partial(const float* __restrict__ q, const _Float16* __restrict__ kv,
                  const int* __restrict__ members, const int* __restrict__ offsets,
                  float* __restrict__ pm, float* __restrict__ pl,
                  float* __restrict__ po) {
    const int c = blockIdx.x, h = blockIdx.y, s = blockIdx.z;
    const int tid = threadIdx.x;
    const int wave = tid >> 6, lane = tid & 63;
    const int start = offsets[c], end = offsets[c + 1];
    const int g = s * 4 + wave;                 // 0..4*SPLITS-1

    float qv[64];
    const bool active = (start + g * 64) < end;
    if (active) {
        const float* qrow = q + c * E_DIM + h * DHD;
#pragma unroll
        for (int d = 0; d < 64; ++d) qv[d] = qrow[d];
    }

    __shared__ float ps[4][64];
    float m = -INFINITY, lsum = 0.f, out = 0.f; // lane owns output dim `lane`

    for (int ch0 = start + g * 64; ch0 < end; ch0 += 4 * ATTN_SPLITS * 64) {
        const int nvalid = min(64, end - ch0);
        const int idx = ch0 + lane;
        const int mi = members[idx < end ? idx : end - 1];
        const _Float16* krow = kv + (size_t)mi * KV_LD + h * DHD;
        float dot = 0.f;
#pragma unroll
        for (int j = 0; j < 8; ++j) {
            f16x8 kr = *(const f16x8*)(krow + j * 8);
#pragma unroll
            for (int e = 0; e < 8; ++e)
                dot = fmaf((float)kr[e], qv[j * 8 + e], dot);
        }
        float sc = (lane < nvalid) ? dot * 0.125f : -INFINITY;
        float cm = sc;
#pragma unroll
        for (int off = 32; off; off >>= 1) cm = fmaxf(cm, __shfl_xor(cm, off));
        const float nm = fmaxf(m, cm);
        const float alpha = __expf(m - nm);
        const float p = (lane < nvalid) ? __expf(sc - nm) : 0.f;
        ps[wave][lane] = p;
        out *= alpha;
        lsum *= alpha;
        m = nm;
        asm volatile("" ::: "memory");
#pragma unroll 16
        for (int j = 0; j < 64; ++j) {
            const int nj = __shfl(mi, j);
            const float pj = ps[wave][j];
            const float vv = (float)kv[(size_t)nj * KV_LD + E_DIM + h * DHD + lane];
            out = fmaf(pj, vv, out);
            lsum += pj;
        }
    }

    __shared__ float rm[4], rl[4], racc[4][64];
    racc[wave][lane] = out;
    if (lane == 0) { rm[wave] = m; rl[wave] = lsum; }
    __syncthreads();
    if (wave == 0) {
        float M = fmaxf(fmaxf(rm[0], rm[1]), fmaxf(rm[2], rm[3]));
        float o = 0.f, Lt = 0.f;
#pragma unroll
        for (int w = 0; w < 4; ++w) {
            // guard: rm[w]==-inf (empty wave) AND possibly M==-inf (all empty)
            // -> exp(-inf - -inf) = NaN without the guard. [R10 NaN bug]
            const float al = (rm[w] > -INFINITY) ? __expf(rm[w] - M) : 0.f;
            o  += al * racc[w][lane];
            Lt += al * rl[w];
        }
        const int pidx = (c * H_HEADS + h) * ATTN_SPLITS + s;
        po[pidx * 64 + lane] = o;      // 0 for all-empty block
        if (lane == 0) { pm[pidx] = M; pl[pidx] = Lt; }
    }
}

// ---------------------------------------------------------------------------
// Combine ATTN_SPLITS partials for all 8 heads of class c into LDS xrow,
// then proto = xrow @ Wo + bo; out (+)= coef_l * proto.
// ---------------------------------------------------------------------------
__global__ __launch_bounds__(256)
void proto_accum(const float* __restrict__ pm, const float* __restrict__ pl,
                 const float* __restrict__ po, const float* __restrict__ Wo,
                 const float* __restrict__ bo, const float* __restrict__ lvlw,
                 const float* __restrict__ lvlt, int l, float* __restrict__ out) {
    const int c = blockIdx.x;
    const int tid = threadIdx.x;
    const int wave = tid >> 6, lane = tid & 63;
    __shared__ float xrow[E_DIM];
#pragma unroll
    for (int hh = wave; hh < H_HEADS; hh += 4) {
        const int ch = c * H_HEADS + hh;
        float M = -INFINITY;
#pragma unroll
        for (int s = 0; s < ATTN_SPLITS; ++s) M = fmaxf(M, pm[ch * ATTN_SPLITS + s]);
        float o = 0.f, Lt = 0.f;
#pragma unroll
        for (int s = 0; s < ATTN_SPLITS; ++s) {
            const int pidx = ch * ATTN_SPLITS + s;
            // guard empty split: pm=-inf -> weight 0 (avoids 0*NaN / exp NaN)
            const float al = (pm[pidx] > -INFINITY) ? __expf(pm[pidx] - M) : 0.f;
            o  += al * po[pidx * 64 + lane];
            Lt += al * pl[pidx];
        }
        xrow[hh * 64 + lane] = o / Lt;
    }
    __syncthreads();

    float a0 = 0.f, a1 = 0.f;
#pragma unroll 8
    for (int k = 0; k < E_DIM; ++k) {
        float cv = xrow[k];
        a0 = fmaf(cv, Wo[(size_t)k * E_DIM + tid], a0);
        a1 = fmaf(cv, Wo[(size_t)k * E_DIM + tid + 256], a1);
    }
    float w0 = lvlw[0], w1 = lvlw[1], w2 = lvlw[2];
    float mx = fmaxf(w0, fmaxf(w1, w2));
    float e0 = expf(w0 - mx), e1 = expf(w1 - mx), e2 = expf(w2 - mx);
    float ssum = e0 + e1 + e2;
    float lw = (l == 0 ? e0 : (l == 1 ? e1 : e2)) / ssum;
    float coef = lw / lvlt[l];
    float r0 = (a0 + bo[tid]) * coef;
    float r1 = (a1 + bo[tid + 256]) * coef;
    if (l == 0) {
        out[c * E_DIM + tid]       = r0;
        out[c * E_DIM + tid + 256] = r1;
    } else {
        out[c * E_DIM + tid]       += r0;
        out[c * E_DIM + tid + 256] += r1;
    }
}

// ---------------------------------------------------------------------------
extern "C" void kernel_launch(void* const* d_in, const int* in_sizes, int n_in,
                              void* d_out, int out_size, void* d_ws, size_t ws_size,
                              hipStream_t stream) {
    const float* X      = (const float*)d_in[0];
    const int*   labels = (const int*)  d_in[1];
    const float* W1     = (const float*)d_in[2];
    const float* b1     = (const float*)d_in[3];   // [3,512] flat == fused bias
    const float* gamma  = (const float*)d_in[4];
    const float* beta   = (const float*)d_in[5];
    const float* W2     = (const float*)d_in[6];
    const float* b2     = (const float*)d_in[7];
    const float* Wq     = (const float*)d_in[8];
    const float* bq     = (const float*)d_in[9];
    const float* Wk     = (const float*)d_in[10];
    const float* bk     = (const float*)d_in[11];
    const float* Wv     = (const float*)d_in[12];
    const float* bv     = (const float*)d_in[13];
    const float* Wo     = (const float*)d_in[14];
    const float* bo     = (const float*)d_in[15];
    const float* lvlw   = (const float*)d_in[16];
    const float* lvlt   = (const float*)d_in[17];
    float* out = (float*)d_out;

    // Workspace carve (~401 MB of the 512 MiB ws)
    char* p = (char*)d_ws;
    const size_t MSZ = (size_t)E_DIM * E_DIM;                       // 262144
    _Float16* Xh      = (_Float16*)p; p += (size_t)N_SUP * E_DIM * 2;         // 64 MB
    _Float16* bufPall = (_Float16*)p; p += (size_t)N_SUP * E_DIM * L_LEV * 2; // 192 MB
    _Float16* bufKV   = (_Float16*)p; p += (size_t)N_SUP * KV_LD * 2;         // 128 MB
    _Float16* W1allT  = (_Float16*)p; p += L_LEV * MSZ * 2;
    _Float16* WkvqT   = (_Float16*)p; p += 3 * MSZ * 2;
    _Float16* W2f16   = (_Float16*)p; p += L_LEV * MSZ * 2;
    _Float16* W2compT = (_Float16*)p; p += (size_t)L_LEV * 1536 * E_DIM * 2;
    float* zeros512 = (float*)p; p += E_DIM * sizeof(float);
    float* bcomp = (float*)p; p += L_LEV * 1536 * sizeof(float);
    float* hpart = (float*)p; p += (size_t)L_LEV * C_CLS * CTX_SPLITS * E_DIM * sizeof(float); // 6 MB
    float* qb    = (float*)p; p += (size_t)L_LEV * C_CLS * E_DIM * sizeof(float);
    float* pm    = (float*)p; p += C_CLS * H_HEADS * ATTN_SPLITS * sizeof(float);
    float* pl    = (float*)p; p += C_CLS * H_HEADS * ATTN_SPLITS * sizeof(float);
    float* po    = (float*)p; p += (size_t)C_CLS * H_HEADS * ATTN_SPLITS * 64 * sizeof(float);
    int* counts      = (int*)p; p += 256;
    int* offs        = (int*)p; p += 512;
    int* members     = (int*)p; p += (size_t)N_SUP * sizeof(int);
    int* blockCounts = (int*)p; p += (size_t)SCAT_BLOCKS * C_CLS * sizeof(int);
    int* blockOffs   = (int*)p; p += (size_t)SCAT_BLOCKS * C_CLS * sizeof(int);

    // Class membership: contention-free counting sort
    label_block_hist<<<SCAT_BLOCKS, 256, 0, stream>>>(labels, blockCounts);
    scan_offsets<<<1, 64, 0, stream>>>(blockCounts, counts, offs, blockOffs);
    scatter_sorted<<<SCAT_BLOCKS, 256, 0, stream>>>(labels, blockOffs, members);

    // Conversions / transposes
    conv32to16<<<(N_SUP * E_DIM / 4) / 256, 256, 0, stream>>>(X, Xh, N_SUP * E_DIM / 4);
    conv32to16<<<(int)(L_LEV * MSZ / 4 / 256), 256, 0, stream>>>(W2, W2f16, L_LEV * MSZ / 4);
    transpose_all<<<dim3(16, 16, 6), 256, 0, stream>>>(W1, Wk, Wv, Wq, W1allT, WkvqT);
    zero_f32<<<2, 256, 0, stream>>>(zeros512, E_DIM);

    // Composed weights: W2compT_l = [WkT;WvT;WqT] @ W2T_l  (fp16 MFMA, batched)
    // M=1536 (6 row-tiles), N=512 (2 col-tiles)
    hgemm256<<<dim3(6 * 2, L_LEV), 512, 0, stream>>>(
        WkvqT, E_DIM, 0, W2f16, MSZ, zeros512, 0,
        W2compT, E_DIM, (size_t)1536 * E_DIM, 2);
    bias_compose<<<dim3(6, L_LEV), 256, 0, stream>>>(b2, Wk, Wv, Wq, bk, bv, bq, bcomp);

    const int nRowT = N_SUP / 256;   // 256 row tiles
    // Fused pre = X @ [W1_0|W1_1|W1_2] + b1  -> bufPall [N x 1536]
    hgemm256<<<dim3(nRowT * 6, 1), 512, 0, stream>>>(
        Xh, E_DIM, 0, W1allT, 0, b1, 0, bufPall, L_LEV * E_DIM, 0, 6);
    // LN+ReLU for all 3 levels (bufPall now holds h)
    ln_relu_all<<<dim3(N_SUP / 4, L_LEV), 256, 0, stream>>>(bufPall, gamma, beta);

    // Level-independent tail, batched once: segment-sum partials + q
    ctx_partial<<<dim3(C_CLS, CTX_SPLITS, L_LEV), 256, 0, stream>>>(
        bufPall, members, offs, hpart);
    row_gemm_q<<<dim3(C_CLS, L_LEV), 256, 0, stream>>>(
        hpart, counts, W2compT, bcomp, qb);

    for (int l = 0; l < L_LEV; ++l) {
        // [K|V] = h_l @ (W2_l@[Wk|Wv]) + composed bias  -> bufKV [N x 1024]
        hgemm256<<<dim3(nRowT * 4, 1), 512, 0, stream>>>(
            bufPall + (size_t)l * E_DIM, L_LEV * E_DIM, 0,
            W2compT + (size_t)l * 1536 * E_DIM, 0,
            bcomp + l * 1536, 0, bufKV, KV_LD, 0, 4);
        attn_partial<<<dim3(C_CLS, H_HEADS, ATTN_SPLITS), 256, 0, stream>>>(
            qb + (size_t)l * C_CLS * E_DIM, bufKV, members, offs, pm, pl, po);
        proto_accum<<<C_CLS, 256, 0, stream>>>(pm, pl, po, Wo, bo, lvlw, lvlt, l, out);
    }
}

// Round 4
// 960.779 us; speedup vs baseline: 1.0807x; 1.0745x over previous
//
#include <hip/hip_runtime.h>
#include <math.h>

// Problem constants (fixed by the reference)
#define N_SUP 65536
#define E_DIM 512
#define H_HEADS 8
#define C_CLS 64
#define DHD 64
#define L_LEV 3
#define LN_EPS 1e-5f
#define ATTN_SPLITS 8
#define CTX_SPLITS 16
#define SCAT_BLOCKS 256        // N_SUP / 256
#define KV_LD 1024

typedef _Float16 f16x8 __attribute__((ext_vector_type(8)));
typedef _Float16 f16x4 __attribute__((ext_vector_type(4)));
typedef float f32x4 __attribute__((ext_vector_type(4)));

// ---------------------------------------------------------------------------
// async global->LDS copy, 16B per lane (wave-uniform LDS base + lane*16;
// global source address is per-lane).
// ---------------------------------------------------------------------------
__device__ __forceinline__ void gload_lds16(const void* g, void* lds) {
    __builtin_amdgcn_global_load_lds((const __attribute__((address_space(1))) void*)g,
                                     (__attribute__((address_space(3))) void*)lds,
                                     16, 0, 0);
}

// ---------------------------------------------------------------------------
// fp16 GEMM, 256x256 tile, BK=64, 8 waves, faithful m201 4-phase-per-K-tile
// schedule. C[M x Ncols] = A[M x 512] @ B + bias; Bt is B^T [Ncols x 512].
// K=512 -> 8 K-tiles of 64; 2 LDS slots, slot t&1 holds tile t.
//
// Phase p of tile t: { ds_read fr-pair {2p,2p+1} A-frags (+all B in ph0)
//   | issue 2 staging loads | s_barrier | lgkmcnt(0) | setprio(1) | 16 MFMA
//   | setprio(0) | [ph3: vmcnt(6)] | s_barrier }.
// Region-safe staging ledger (writes only after all readers, barrier-sep):
//   A rows [32p,32p+32)+[128+32p,..) read in phase p; B all read in ph0.
//   t ph0: A-pass{1,3}(t+1)  [read by t+1 phases 2,3; slot t+1 idle]
//   t ph1: B-pass{0,1}(t+2)  [B(slot) drained at t ph0]
//   t ph2: B-pass{2,3}(t+2)
//   t ph3: A-pass{0,2}(t+2)  [drained by end of t ph1]
// vmcnt once per K-tile at ph3: 6 = 3 two-load groups newer than tile t+1's
// last load (m201's counted-N formula); vmcnt(0) only at t==6; never 0 in
// steady state. Prologue: tile0 (8 loads) + tile1 (6 loads), vmcnt(6).
// Swizzle: LDS(r,b)=global(r, b^(r&7)) via pre-swizzled source; read side
// b=(4*kk+q)^(m&7) -> involution cancels -> conflict-free (measured 0).
// ---------------------------------------------------------------------------
__global__ __launch_bounds__(512, 2)
void hgemm256(const _Float16* __restrict__ A, int lda, size_t aStride,
              const _Float16* __restrict__ Bt, size_t btStride,
              const float* __restrict__ bias, size_t biasStride,
              _Float16* __restrict__ C, int ldc, size_t cStride, int nCol) {
    const int z = blockIdx.y;
    A += z * aStride; Bt += z * btStride; bias += z * biasStride; C += z * cStride;

    const int nRow = gridDim.x / nCol;
    const int R = nRow < 64 ? nRow : 64;
    const int bid = blockIdx.x;
    const int bandSz = R * nCol;
    const int band = bid / bandSz;
    const int rem = bid % bandSz;
    const int colT = rem / R;
    const int rowT = band * R + (rem % R);
    const int row0 = rowT * 256, col0 = colT * 256;

    // [slot][A/B][256 rows][64 f16] = 128 KiB
    __shared__ _Float16 smem[2][2][256][64];

    const int tid = threadIdx.x;
    const int wave = tid >> 6, lane = tid & 63;
    const int wm2 = (wave & 1) * 128;     // M half of this wave
    const int wn4 = (wave >> 1) * 64;     // N quarter of this wave
    const int m = lane & 15, q = lane >> 4;

    // staging: thread -> (row sr per 64-row pass, 16B-block sb), swizzled src
    const int sr = tid >> 3;
    const int sb = tid & 7;
    const int sblk = sb ^ (sr & 7);       // (row&7)==(sr&7) for every pass

    const _Float16* Asrc = A + (size_t)(row0 + sr) * lda + sblk * 8;
    const _Float16* Bsrc = Bt + (size_t)(col0 + sr) * E_DIM + sblk * 8;
    const size_t aPass = (size_t)64 * lda;   // 64 rows per pass
    const size_t bPass = (size_t)64 * E_DIM;

#define SLOTA(T) ((char*)&smem[(T) & 1][0][0][0] + wave * 1024)
#define SLOTB(T) ((char*)&smem[(T) & 1][1][0][0] + wave * 1024)
#define STAGE_A(T, p) gload_lds16(Asrc + (size_t)(p) * aPass + (T) * 64, SLOTA(T) + (p) * 8192)
#define STAGE_B(T, p) gload_lds16(Bsrc + (size_t)(p) * bPass + (T) * 64, SLOTB(T) + (p) * 8192)

    f32x4 acc[8][4];
#pragma unroll
    for (int i = 0; i < 8; ++i)
#pragma unroll
        for (int j = 0; j < 4; ++j) acc[i][j] = (f32x4){0.f, 0.f, 0.f, 0.f};

    // element offsets of the two kk sub-steps (in f16), swizzled
    const int c0k = ((q) ^ (m & 7)) * 8;
    const int c1k = ((4 + q) ^ (m & 7)) * 8;

    // prologue: tile0 fully (8), tile1 partially (6)
    STAGE_B(0, 0); STAGE_B(0, 1); STAGE_B(0, 2); STAGE_B(0, 3);
    STAGE_A(0, 0); STAGE_A(0, 2); STAGE_A(0, 1); STAGE_A(0, 3);
    STAGE_B(1, 0); STAGE_B(1, 1); STAGE_B(1, 2); STAGE_B(1, 3);
    STAGE_A(1, 0); STAGE_A(1, 2);
    asm volatile("s_waitcnt vmcnt(6)" ::: "memory");   // tile0 landed
    __builtin_amdgcn_s_barrier();

    for (int t = 0; t < 8; ++t) {
        const _Float16* As = &smem[t & 1][0][0][0];
        const _Float16* Bs = &smem[t & 1][1][0][0];
        f16x8 b0[4], b1[4];
        f16x8 a0[2], a1[2];

        // ---------------- phase 0: all B + A fr{0,1}; stage A1,A3(t+1) ----
#pragma unroll
        for (int fc = 0; fc < 4; ++fc) {
            const int rb = (wn4 + fc * 16 + m) * 64;
            b0[fc] = *(const f16x8*)&Bs[rb + c0k];
            b1[fc] = *(const f16x8*)&Bs[rb + c1k];
        }
#pragma unroll
        for (int i = 0; i < 2; ++i) {
            const int rb = (wm2 + i * 16 + m) * 64;
            a0[i] = *(const f16x8*)&As[rb + c0k];
            a1[i] = *(const f16x8*)&As[rb + c1k];
        }
        if (t < 7) { STAGE_A(t + 1, 1); STAGE_A(t + 1, 3); }
        __builtin_amdgcn_s_barrier();
        asm volatile("s_waitcnt lgkmcnt(0)" ::: "memory");
        __builtin_amdgcn_s_setprio(1);
#pragma unroll
        for (int i = 0; i < 2; ++i)
#pragma unroll
            for (int fc = 0; fc < 4; ++fc) {
                acc[i][fc] = __builtin_amdgcn_mfma_f32_16x16x32_f16(a0[i], b0[fc], acc[i][fc], 0, 0, 0);
                acc[i][fc] = __builtin_amdgcn_mfma_f32_16x16x32_f16(a1[i], b1[fc], acc[i][fc], 0, 0, 0);
            }
        __builtin_amdgcn_s_setprio(0);
        __builtin_amdgcn_s_barrier();

        // ---------------- phases 1..3 -------------------------------------
#pragma unroll
        for (int p = 1; p < 4; ++p) {
#pragma unroll
            for (int i = 0; i < 2; ++i) {
                const int rb = (wm2 + (2 * p + i) * 16 + m) * 64;
                a0[i] = *(const f16x8*)&As[rb + c0k];
                a1[i] = *(const f16x8*)&As[rb + c1k];
            }
            if (p == 1) { if (t < 6) { STAGE_B(t + 2, 0); STAGE_B(t + 2, 1); } }
            if (p == 2) { if (t < 6) { STAGE_B(t + 2, 2); STAGE_B(t + 2, 3); } }
            if (p == 3) { if (t < 6) { STAGE_A(t + 2, 0); STAGE_A(t + 2, 2); } }
            __builtin_amdgcn_s_barrier();
            asm volatile("s_waitcnt lgkmcnt(0)" ::: "memory");
            __builtin_amdgcn_s_setprio(1);
#pragma unroll
            for (int i = 0; i < 2; ++i)
#pragma unroll
                for (int fc = 0; fc < 4; ++fc) {
                    acc[2 * p + i][fc] = __builtin_amdgcn_mfma_f32_16x16x32_f16(a0[i], b0[fc], acc[2 * p + i][fc], 0, 0, 0);
                    acc[2 * p + i][fc] = __builtin_amdgcn_mfma_f32_16x16x32_f16(a1[i], b1[fc], acc[2 * p + i][fc], 0, 0, 0);
                }
            __builtin_amdgcn_s_setprio(0);
            if (p == 3) {
                // counted vmcnt once per K-tile: tile t+1 complete when the
                // 6 newer staged loads (B01,B23,A02 of t+2) may remain.
                if (t < 6)       asm volatile("s_waitcnt vmcnt(6)" ::: "memory");
                else if (t == 6) asm volatile("s_waitcnt vmcnt(0)" ::: "memory");
            }
            __builtin_amdgcn_s_barrier();
        }
    }
#undef STAGE_A
#undef STAGE_B
#undef SLOTA
#undef SLOTB

    // C/D layout: col = lane&15, row = (lane>>4)*4 + reg
#pragma unroll
    for (int fr = 0; fr < 8; ++fr) {
        const int rbase = row0 + wm2 + fr * 16 + q * 4;
#pragma unroll
        for (int fc = 0; fc < 4; ++fc) {
            const int col = col0 + wn4 + fc * 16 + m;
            const float bv = bias[col];
#pragma unroll
            for (int r = 0; r < 4; ++r)
                C[(size_t)(rbase + r) * ldc + col] = (_Float16)(acc[fr][fc][r] + bv);
        }
    }
}

// ---------------------------------------------------------------------------
// fp32 -> fp16 elementwise (vectorized x4)
// ---------------------------------------------------------------------------
__global__ __launch_bounds__(256)
void conv32to16(const float* __restrict__ in, _Float16* __restrict__ out, int n4) {
    int i = blockIdx.x * 256 + threadIdx.x;
    if (i < n4) {
        f32x4 v = ((const f32x4*)in)[i];
        f16x4 o = {(_Float16)v[0], (_Float16)v[1], (_Float16)v[2], (_Float16)v[3]};
        ((f16x4*)out)[i] = o;
    }
}

// ---------------------------------------------------------------------------
// Batched weight transpose fp32->fp16: z 0..2: W1[l]->W1allT; z 3..5:
// Wk,Wv,Wq -> WkvqT rows 0/512/1024.
// ---------------------------------------------------------------------------
__global__ __launch_bounds__(256)
void transpose_all(const float* __restrict__ W1, const float* __restrict__ Wk,
                   const float* __restrict__ Wv, const float* __restrict__ Wq,
                   _Float16* __restrict__ W1allT, _Float16* __restrict__ WkvqT) {
    const int z = blockIdx.z;
    const float* src;
    _Float16* dst;
    const size_t MSZ = (size_t)E_DIM * E_DIM;
    if (z < 3)       { src = W1 + z * MSZ; dst = W1allT + z * MSZ; }
    else if (z == 3) { src = Wk;           dst = WkvqT; }
    else if (z == 4) { src = Wv;           dst = WkvqT + MSZ; }
    else             { src = Wq;           dst = WkvqT + 2 * MSZ; }

    __shared__ float t[32][33];
    const int k0 = blockIdx.x * 32, n0 = blockIdx.y * 32;
    const int tx = threadIdx.x & 31, ty = threadIdx.x >> 5;
#pragma unroll
    for (int r = 0; r < 32; r += 8)
        t[ty + r][tx] = src[(size_t)(k0 + ty + r) * E_DIM + n0 + tx];
    __syncthreads();
#pragma unroll
    for (int r = 0; r < 32; r += 8)
        dst[(size_t)(n0 + ty + r) * E_DIM + k0 + tx] = (_Float16)t[tx][ty + r];
}

// ---------------------------------------------------------------------------
// Composed biases: bcomp[l][n] for n<512: b2_l@Wk + bk; [512,1024): Wv/bv;
// [1024,1536): Wq/bq.
// ---------------------------------------------------------------------------
__global__ __launch_bounds__(256)
void bias_compose(const float* __restrict__ b2, const float* __restrict__ Wk,
                  const float* __restrict__ Wv, const float* __restrict__ Wq,
                  const float* __restrict__ bk, const float* __restrict__ bv,
                  const float* __restrict__ bq, float* __restrict__ bcomp) {
    const int l = blockIdx.y;
    const int n = blockIdx.x * 256 + threadIdx.x;   // 0..1535
    const float* W; const float* bb; int nn;
    if (n < 512)       { W = Wk; bb = bk; nn = n; }
    else if (n < 1024) { W = Wv; bb = bv; nn = n - 512; }
    else               { W = Wq; bb = bq; nn = n - 1024; }
    float acc = 0.f;
    for (int j = 0; j < E_DIM; ++j)
        acc = fmaf(b2[l * E_DIM + j], W[(size_t)j * E_DIM + nn], acc);
    bcomp[l * 1536 + n] = acc + bb[nn];
}

// ---------------------------------------------------------------------------
// LayerNorm + ReLU over bufPall [N x 1536], all 3 levels in one dispatch.
// ---------------------------------------------------------------------------
__global__ __launch_bounds__(256)
void ln_relu_all(_Float16* __restrict__ P, const float* __restrict__ gamma,
                 const float* __restrict__ beta) {
    const int row = blockIdx.x * 4 + (threadIdx.x >> 6);
    const int l = blockIdx.y;
    const int lane = threadIdx.x & 63;
    _Float16* prow = P + (size_t)row * (L_LEV * E_DIM) + l * E_DIM + lane * 8;
    const float* g = gamma + l * E_DIM + lane * 8;
    const float* b = beta  + l * E_DIM + lane * 8;
    f16x8 v = *(const f16x8*)prow;
    float x[8];
    float s = 0.f, s2 = 0.f;
#pragma unroll
    for (int e = 0; e < 8; ++e) {
        x[e] = (float)v[e];
        s += x[e];
        s2 = fmaf(x[e], x[e], s2);
    }
#pragma unroll
    for (int off = 32; off; off >>= 1) {
        s  += __shfl_xor(s, off);
        s2 += __shfl_xor(s2, off);
    }
    const float mean = s * (1.f / E_DIM);
    const float var  = s2 * (1.f / E_DIM) - mean * mean;
    const float rstd = rsqrtf(var + LN_EPS);
    f32x4 g0 = *(const f32x4*)g;
    f32x4 g1 = *(const f32x4*)(g + 4);
    f32x4 b0 = *(const f32x4*)b;
    f32x4 b1 = *(const f32x4*)(b + 4);
    f16x8 o;
#pragma unroll
    for (int e = 0; e < 4; ++e) {
        o[e]     = (_Float16)fmaxf(fmaf((x[e]     - mean) * rstd, g0[e], b0[e]), 0.f);
        o[e + 4] = (_Float16)fmaxf(fmaf((x[e + 4] - mean) * rstd, g1[e], b1[e]), 0.f);
    }
    *(f16x8*)prow = o;
}

// ---------------------------------------------------------------------------
// Contention-free counting sort
// ---------------------------------------------------------------------------
__global__ __launch_bounds__(256)
void label_block_hist(const int* __restrict__ labels, int* __restrict__ blockCounts) {
    __shared__ int h[C_CLS];
    const int tid = threadIdx.x;
    if (tid < C_CLS) h[tid] = 0;
    __syncthreads();
    atomicAdd(&h[labels[blockIdx.x * 256 + tid]], 1);
    __syncthreads();
    if (tid < C_CLS) blockCounts[blockIdx.x * C_CLS + tid] = h[tid];
}

__global__ __launch_bounds__(64)
void scan_offsets(const int* __restrict__ blockCounts, int* __restrict__ counts,
                  int* __restrict__ offs, int* __restrict__ blockOffs) {
    const int c = threadIdx.x;
    int total = 0;
    for (int b = 0; b < SCAT_BLOCKS; ++b) total += blockCounts[b * C_CLS + c];
    counts[c] = total;
    __shared__ int tot[C_CLS];
    tot[c] = total;
    __syncthreads();
    int off = 0;
    for (int cc = 0; cc < c; ++cc) off += tot[cc];
    offs[c] = off;
    if (c == C_CLS - 1) offs[C_CLS] = off + total;
    int run = off;
    for (int b = 0; b < SCAT_BLOCKS; ++b) {
        blockOffs[b * C_CLS + c] = run;
        run += blockCounts[b * C_CLS + c];
    }
}

__global__ __launch_bounds__(256)
void scatter_sorted(const int* __restrict__ labels, const int* __restrict__ blockOffs,
                    int* __restrict__ members) {
    __shared__ int cur[C_CLS];
    const int tid = threadIdx.x;
    if (tid < C_CLS) cur[tid] = blockOffs[blockIdx.x * C_CLS + tid];
    __syncthreads();
    const int i = blockIdx.x * 256 + tid;
    const int c = labels[i];
    const int p = atomicAdd(&cur[c], 1);
    members[p] = i;
}

__global__ __launch_bounds__(256)
void zero_f32(float* __restrict__ p, int n) {
    int i = blockIdx.x * 256 + threadIdx.x;
    if (i < n) p[i] = 0.f;
}

// ---------------------------------------------------------------------------
// hpart[l][c][split][:] = partial segment-sum of h_l over class members.
// Batched over levels (grid.z); write-based (no atomics, no zero pass).
// ---------------------------------------------------------------------------
__global__ __launch_bounds__(256)
void ctx_partial(const _Float16* __restrict__ P, const int* __restrict__ members,
                 const int* __restrict__ offsets, float* __restrict__ hpart) {
    const int c = blockIdx.x, split = blockIdx.y, l = blockIdx.z;
    const _Float16* src = P + (size_t)l * E_DIM;
    const int tid = threadIdx.x;
    const int wave = tid >> 6, lane = tid & 63;
    const int start = offsets[c], end = offsets[c + 1];
    const int wg = split * 4 + wave;
    const int stride = 4 * CTX_SPLITS;
    const int ld = L_LEV * E_DIM;

    float acc[8];
#pragma unroll
    for (int e = 0; e < 8; ++e) acc[e] = 0.f;

    int i = start + wg;
    for (; i + stride < end; i += 2 * stride) {
        const int n0 = members[i];
        const int n1 = members[i + stride];
        f16x8 r0 = *(const f16x8*)(src + (size_t)n0 * ld + lane * 8);
        f16x8 r1 = *(const f16x8*)(src + (size_t)n1 * ld + lane * 8);
#pragma unroll
        for (int e = 0; e < 8; ++e) acc[e] += (float)r0[e] + (float)r1[e];
    }
    if (i < end) {
        const int n0 = members[i];
        f16x8 r0 = *(const f16x8*)(src + (size_t)n0 * ld + lane * 8);
#pragma unroll
        for (int e = 0; e < 8; ++e) acc[e] += (float)r0[e];
    }

    __shared__ float red[4][64][8];
#pragma unroll
    for (int e = 0; e < 8; ++e) red[wave][lane][e] = acc[e];
    __syncthreads();
    float* dst = hpart + (((size_t)l * C_CLS + c) * CTX_SPLITS + split) * E_DIM;
#pragma unroll
    for (int t = 0; t < 2; ++t) {
        const int col = tid * 2 + t;
        const int ln = col >> 3, e = col & 7;
        dst[col] = red[0][ln][e] + red[1][ln][e] + red[2][ln][e] + red[3][ln][e];
    }
}

// ---------------------------------------------------------------------------
// q[l][c][:] = (mean of h_l over class c) @ (W2_l@Wq) + composed bias.
// Batched over levels (grid.y). Reduces the CTX_SPLITS partials inline.
// ---------------------------------------------------------------------------
__global__ __launch_bounds__(256)
void row_gemm_q(const float* __restrict__ hpart, const int* __restrict__ counts,
                const _Float16* __restrict__ W2compT, const float* __restrict__ bcomp,
                float* __restrict__ q) {
    const int c = blockIdx.x, l = blockIdx.y;
    const int tid = threadIdx.x;
    const float inv = 1.f / (float)counts[c];
    __shared__ float xrow[E_DIM];
    const float* hp = hpart + ((size_t)l * C_CLS + c) * CTX_SPLITS * E_DIM;
    float s0 = 0.f, s1 = 0.f;
#pragma unroll
    for (int s = 0; s < CTX_SPLITS; ++s) {
        s0 += hp[s * E_DIM + tid];
        s1 += hp[s * E_DIM + tid + 256];
    }
    xrow[tid]       = s0 * inv;
    xrow[tid + 256] = s1 * inv;
    __syncthreads();

    const _Float16* Wq = W2compT + (size_t)l * 1536 * E_DIM + (size_t)1024 * E_DIM;
    const float* bias = bcomp + l * 1536 + 1024;
    const int n0 = tid, n1 = tid + 256;
    float a0 = 0.f, a1 = 0.f;
#pragma unroll 4
    for (int k0 = 0; k0 < E_DIM; k0 += 8) {
        f16x8 w0 = *(const f16x8*)(Wq + (size_t)n0 * E_DIM + k0);
        f16x8 w1 = *(const f16x8*)(Wq + (size_t)n1 * E_DIM + k0);
#pragma unroll
        for (int e = 0; e < 8; ++e) {
            const float xv = xrow[k0 + e];
            a0 = fmaf(xv, (float)w0[e], a0);
            a1 = fmaf(xv, (float)w1[e], a1);
        }
    }
    float* qq = q + (size_t)l * C_CLS * E_DIM;
    qq[c * E_DIM + n0] = a0 + bias[n0];
    qq[c * E_DIM + n1] = a1 + bias[n1];
}

// ---------------------------------------------------------------------------
// Segment attention, phase 1. K/V packed: row n = [K(512) | V(512)] in bufKV.
// grid (C, H, ATTN_SPLITS). NOTE: splits/waves beyond the member count are
// legitimately empty (m=-inf); the combine must guard exp(-inf - -inf).
// ---------------------------------------------------------------------------
__global__ __launch_bounds__(256)
void attn_partial(const float* __restrict__ q, const _Float16* __restrict__ kv,
                  const int* __restrict__ members, const int* __restrict__ offsets,
                  float* __restrict__ pm, float* __restrict__ pl,
                  float* __restrict__ po) {
    const int c = blockIdx.x, h = blockIdx.y, s = blockIdx.z;
    const int tid = threadIdx.x;
    const int wave = tid >> 6, lane = tid & 63;
    const int start = offsets[c], end = offsets[c + 1];
    const int g = s * 4 + wave;                 // 0..4*SPLITS-1

    float qv[64];
    const bool active = (start + g * 64) < end;
    if (active) {
        const float* qrow = q + c * E_DIM + h * DHD;
#pragma unroll
        for (int d = 0; d < 64; ++d) qv[d] = qrow[d];
    }

    __shared__ float ps[4][64];
    float m = -INFINITY, lsum = 0.f, out = 0.f; // lane owns output dim `lane`

    for (int ch0 = start + g * 64; ch0 < end; ch0 += 4 * ATTN_SPLITS * 64) {
        const int nvalid = min(64, end - ch0);
        const int idx = ch0 + lane;
        const int mi = members[idx < end ? idx : end - 1];
        const _Float16* krow = kv + (size_t)mi * KV_LD + h * DHD;
        float dot = 0.f;
#pragma unroll
        for (int j = 0; j < 8; ++j) {
            f16x8 kr = *(const f16x8*)(krow + j * 8);
#pragma unroll
            for (int e = 0; e < 8; ++e)
                dot = fmaf((float)kr[e], qv[j * 8 + e], dot);
        }
        float sc = (lane < nvalid) ? dot * 0.125f : -INFINITY;
        float cm = sc;
#pragma unroll
        for (int off = 32; off; off >>= 1) cm = fmaxf(cm, __shfl_xor(cm, off));
        const float nm = fmaxf(m, cm);
        const float alpha = __expf(m - nm);
        const float p = (lane < nvalid) ? __expf(sc - nm) : 0.f;
        ps[wave][lane] = p;
        out *= alpha;
        lsum *= alpha;
        m = nm;
        asm volatile("" ::: "memory");
#pragma unroll 16
        for (int j = 0; j < 64; ++j) {
            const int nj = __shfl(mi, j);
            const float pj = ps[wave][j];
            const float vv = (float)kv[(size_t)nj * KV_LD + E_DIM + h * DHD + lane];
            out = fmaf(pj, vv, out);
            lsum += pj;
        }
    }

    __shared__ float rm[4], rl[4], racc[4][64];
    racc[wave][lane] = out;
    if (lane == 0) { rm[wave] = m; rl[wave] = lsum; }
    __syncthreads();
    if (wave == 0) {
        float M = fmaxf(fmaxf(rm[0], rm[1]), fmaxf(rm[2], rm[3]));
        float o = 0.f, Lt = 0.f;
#pragma unroll
        for (int w = 0; w < 4; ++w) {
            // guard: rm[w]==-inf (empty wave) AND possibly M==-inf (all empty)
            // -> exp(-inf - -inf) = NaN without the guard. [R10 NaN bug]
            const float al = (rm[w] > -INFINITY) ? __expf(rm[w] - M) : 0.f;
            o  += al * racc[w][lane];
            Lt += al * rl[w];
        }
        const int pidx = (c * H_HEADS + h) * ATTN_SPLITS + s;
        po[pidx * 64 + lane] = o;      // 0 for all-empty block
        if (lane == 0) { pm[pidx] = M; pl[pidx] = Lt; }
    }
}

// ---------------------------------------------------------------------------
// Combine ATTN_SPLITS partials for all 8 heads of class c into LDS xrow,
// then proto = xrow @ Wo + bo; out (+)= coef_l * proto.
// ---------------------------------------------------------------------------
__global__ __launch_bounds__(256)
void proto_accum(const float* __restrict__ pm, const float* __restrict__ pl,
                 const float* __restrict__ po, const float* __restrict__ Wo,
                 const float* __restrict__ bo, const float* __restrict__ lvlw,
                 const float* __restrict__ lvlt, int l, float* __restrict__ out) {
    const int c = blockIdx.x;
    const int tid = threadIdx.x;
    const int wave = tid >> 6, lane = tid & 63;
    __shared__ float xrow[E_DIM];
#pragma unroll
    for (int hh = wave; hh < H_HEADS; hh += 4) {
        const int ch = c * H_HEADS + hh;
        float M = -INFINITY;
#pragma unroll
        for (int s = 0; s < ATTN_SPLITS; ++s) M = fmaxf(M, pm[ch * ATTN_SPLITS + s]);
        float o = 0.f, Lt = 0.f;
#pragma unroll
        for (int s = 0; s < ATTN_SPLITS; ++s) {
            const int pidx = ch * ATTN_SPLITS + s;
            // guard empty split: pm=-inf -> weight 0 (avoids 0*NaN / exp NaN)
            const float al = (pm[pidx] > -INFINITY) ? __expf(pm[pidx] - M) : 0.f;
            o  += al * po[pidx * 64 + lane];
            Lt += al * pl[pidx];
        }
        xrow[hh * 64 + lane] = o / Lt;
    }
    __syncthreads();

    float a0 = 0.f, a1 = 0.f;
#pragma unroll 8
    for (int k = 0; k < E_DIM; ++k) {
        float cv = xrow[k];
        a0 = fmaf(cv, Wo[(size_t)k * E_DIM + tid], a0);
        a1 = fmaf(cv, Wo[(size_t)k * E_DIM + tid + 256], a1);
    }
    float w0 = lvlw[0], w1 = lvlw[1], w2 = lvlw[2];
    float mx = fmaxf(w0, fmaxf(w1, w2));
    float e0 = expf(w0 - mx), e1 = expf(w1 - mx), e2 = expf(w2 - mx);
    float ssum = e0 + e1 + e2;
    float lw = (l == 0 ? e0 : (l == 1 ? e1 : e2)) / ssum;
    float coef = lw / lvlt[l];
    float r0 = (a0 + bo[tid]) * coef;
    float r1 = (a1 + bo[tid + 256]) * coef;
    if (l == 0) {
        out[c * E_DIM + tid]       = r0;
        out[c * E_DIM + tid + 256] = r1;
    } else {
        out[c * E_DIM + tid]       += r0;
        out[c * E_DIM + tid + 256] += r1;
    }
}

// ---------------------------------------------------------------------------
extern "C" void kernel_launch(void* const* d_in, const int* in_sizes, int n_in,
                              void* d_out, int out_size, void* d_ws, size_t ws_size,
                              hipStream_t stream) {
    const float* X      = (const float*)d_in[0];
    const int*   labels = (const int*)  d_in[1];
    const float* W1     = (const float*)d_in[2];
    const float* b1     = (const float*)d_in[3];   // [3,512] flat == fused bias
    const float* gamma  = (const float*)d_in[4];
    const float* beta   = (const float*)d_in[5];
    const float* W2     = (const float*)d_in[6];
    const float* b2     = (const float*)d_in[7];
    const float* Wq     = (const float*)d_in[8];
    const float* bq     = (const float*)d_in[9];
    const float* Wk     = (const float*)d_in[10];
    const float* bk     = (const float*)d_in[11];
    const float* Wv     = (const float*)d_in[12];
    const float* bv     = (const float*)d_in[13];
    const float* Wo     = (const float*)d_in[14];
    const float* bo     = (const float*)d_in[15];
    const float* lvlw   = (const float*)d_in[16];
    const float* lvlt   = (const float*)d_in[17];
    float* out = (float*)d_out;

    // Workspace carve (~401 MB of the 512 MiB ws)
    char* p = (char*)d_ws;
    const size_t MSZ = (size_t)E_DIM * E_DIM;                       // 262144
    _Float16* Xh      = (_Float16*)p; p += (size_t)N_SUP * E_DIM * 2;         // 64 MB
    _Float16* bufPall = (_Float16*)p; p += (size_t)N_SUP * E_DIM * L_LEV * 2; // 192 MB
    _Float16* bufKV   = (_Float16*)p; p += (size_t)N_SUP * KV_LD * 2;         // 128 MB
    _Float16* W1allT  = (_Float16*)p; p += L_LEV * MSZ * 2;
    _Float16* WkvqT   = (_Float16*)p; p += 3 * MSZ * 2;
    _Float16* W2f16   = (_Float16*)p; p += L_LEV * MSZ * 2;
    _Float16* W2compT = (_Float16*)p; p += (size_t)L_LEV * 1536 * E_DIM * 2;
    float* zeros512 = (float*)p; p += E_DIM * sizeof(float);
    float* bcomp = (float*)p; p += L_LEV * 1536 * sizeof(float);
    float* hpart = (float*)p; p += (size_t)L_LEV * C_CLS * CTX_SPLITS * E_DIM * sizeof(float); // 6 MB
    float* qb    = (float*)p; p += (size_t)L_LEV * C_CLS * E_DIM * sizeof(float);
    float* pm    = (float*)p; p += C_CLS * H_HEADS * ATTN_SPLITS * sizeof(float);
    float* pl    = (float*)p; p += C_CLS * H_HEADS * ATTN_SPLITS * sizeof(float);
    float* po    = (float*)p; p += (size_t)C_CLS * H_HEADS * ATTN_SPLITS * 64 * sizeof(float);
    int* counts      = (int*)p; p += 256;
    int* offs        = (int*)p; p += 512;
    int* members     = (int*)p; p += (size_t)N_SUP * sizeof(int);
    int* blockCounts = (int*)p; p += (size_t)SCAT_BLOCKS * C_CLS * sizeof(int);
    int* blockOffs   = (int*)p; p += (size_t)SCAT_BLOCKS * C_CLS * sizeof(int);

    // Class membership: contention-free counting sort
    label_block_hist<<<SCAT_BLOCKS, 256, 0, stream>>>(labels, blockCounts);
    scan_offsets<<<1, 64, 0, stream>>>(blockCounts, counts, offs, blockOffs);
    scatter_sorted<<<SCAT_BLOCKS, 256, 0, stream>>>(labels, blockOffs, members);

    // Conversions / transposes
    conv32to16<<<(N_SUP * E_DIM / 4) / 256, 256, 0, stream>>>(X, Xh, N_SUP * E_DIM / 4);
    conv32to16<<<(int)(L_LEV * MSZ / 4 / 256), 256, 0, stream>>>(W2, W2f16, L_LEV * MSZ / 4);
    transpose_all<<<dim3(16, 16, 6), 256, 0, stream>>>(W1, Wk, Wv, Wq, W1allT, WkvqT);
    zero_f32<<<2, 256, 0, stream>>>(zeros512, E_DIM);

    // Composed weights: W2compT_l = [WkT;WvT;WqT] @ W2T_l  (fp16 MFMA, batched)
    // M=1536 (6 row-tiles), N=512 (2 col-tiles)
    hgemm256<<<dim3(6 * 2, L_LEV), 512, 0, stream>>>(
        WkvqT, E_DIM, 0, W2f16, MSZ, zeros512, 0,
        W2compT, E_DIM, (size_t)1536 * E_DIM, 2);
    bias_compose<<<dim3(6, L_LEV), 256, 0, stream>>>(b2, Wk, Wv, Wq, bk, bv, bq, bcomp);

    const int nRowT = N_SUP / 256;   // 256 row tiles
    // Fused pre = X @ [W1_0|W1_1|W1_2] + b1  -> bufPall [N x 1536]
    hgemm256<<<dim3(nRowT * 6, 1), 512, 0, stream>>>(
        Xh, E_DIM, 0, W1allT, 0, b1, 0, bufPall, L_LEV * E_DIM, 0, 6);
    // LN+ReLU for all 3 levels (bufPall now holds h)
    ln_relu_all<<<dim3(N_SUP / 4, L_LEV), 256, 0, stream>>>(bufPall, gamma, beta);

    // Level-independent tail, batched once: segment-sum partials + q
    ctx_partial<<<dim3(C_CLS, CTX_SPLITS, L_LEV), 256, 0, stream>>>(
        bufPall, members, offs, hpart);
    row_gemm_q<<<dim3(C_CLS, L_LEV), 256, 0, stream>>>(
        hpart, counts, W2compT, bcomp, qb);

    for (int l = 0; l < L_LEV; ++l) {
        // [K|V] = h_l @ (W2_l@[Wk|Wv]) + composed bias  -> bufKV [N x 1024]
        hgemm256<<<dim3(nRowT * 4, 1), 512, 0, stream>>>(
            bufPall + (size_t)l * E_DIM, L_LEV * E_DIM, 0,
            W2compT + (size_t)l * 1536 * E_DIM, 0,
            bcomp + l * 1536, 0, bufKV, KV_LD, 0, 4);
        attn_partial<<<dim3(C_CLS, H_HEADS, ATTN_SPLITS), 256, 0, stream>>>(
            qb + (size_t)l * C_CLS * E_DIM, bufKV, members, offs, pm, pl, po);
        proto_accum<<<C_CLS, 256, 0, stream>>>(pm, pl, po, Wo, bo, lvlw, lvlt, l, out);
    }
}

// Round 5
// 954.305 us; speedup vs baseline: 1.0880x; 1.0068x over previous
//
#include <hip/hip_runtime.h>
#include <math.h>

// Problem constants (fixed by the reference)
#define N_SUP 65536
#define E_DIM 512
#define H_HEADS 8
#define C_CLS 64
#define DHD 64
#define L_LEV 3
#define LN_EPS 1e-5f
#define ATTN_SPLITS 8
#define CTX_SPLITS 16
#define SCAT_BLOCKS 256        // N_SUP / 256
#define KV_LD 1024

typedef _Float16 f16x8 __attribute__((ext_vector_type(8)));
typedef _Float16 f16x4 __attribute__((ext_vector_type(4)));
typedef float f32x4 __attribute__((ext_vector_type(4)));

// ---------------------------------------------------------------------------
// async global->LDS copy, 16B per lane (wave-uniform LDS base + lane*16;
// global source address is per-lane).
// ---------------------------------------------------------------------------
__device__ __forceinline__ void gload_lds16(const void* g, void* lds) {
    __builtin_amdgcn_global_load_lds((const __attribute__((address_space(1))) void*)g,
                                     (__attribute__((address_space(3))) void*)lds,
                                     16, 0, 0);
}

// ---------------------------------------------------------------------------
// fp16 GEMM, 256x256 tile, BK=64, 8 waves. R5 schedule: intra-tile software
// pipelined ds_reads with counted (compiler-emitted) lgkmcnt + 2 barriers per
// K-tile. C[M x Ncols] = A[M x 512] @ B + bias; Bt is B^T [Ncols x 512].
// K=512 -> 8 K-tiles of 64; 2 LDS slots, slot t&1 holds tile t.
//
// Per tile t (data valid for whole tile after tile-entry barrier):
//   R0: 8 ds_read (b0 fc0-3 @k0, a fr0-3 @k0)
//   R1: 4 ds_read (a fr4-7 @k0)
//   MFMA ph0: acc[0..3][*] += a*b0          (16, all independent)
//   R2: 8 ds_read (b1 @k1, a fr0-3 @k1)
//   MFMA ph1: acc[4..7][*] += a*b0
//   R3: 4 ds_read (a fr4-7 @k1)
//   MFMA ph2: acc[0..3][*] += a*b1
//   lgkm(0) -> barrier#1   [every wave's reads of slot t&1 COMPLETE]
//   STAGE all 8 passes of tile t+2 into slot t&1   (race-free by #1)
//   MFMA ph3: acc[4..7][*] += a*b1          (registers only)
//   vmcnt(8) [t+1 landed; 8 outstanding = t+2's] -> barrier#2
// Compiler emits precise counted lgkmcnt(N) for its own ds_reads (m97), so
// each MFMA block waits only on reads issued >=1 MFMA-block earlier -- the
// R4 exposed lgkmcnt(0)-per-phase latency is gone. The asm "memory" clobbers
// on vmcnt/lgkm pin cross-barrier ordering for the compiler; s_barrier pins
// the waves. vmcnt(0) only at t==6 (drain for last tile).
// Swizzle: LDS(r,b)=global(r, b^(r&7)) via pre-swizzled source; read side
// b=(4*kk+q)^(m&7) -> involution cancels -> conflict-free (measured 0).
// ---------------------------------------------------------------------------
__global__ __launch_bounds__(512, 2)
void hgemm256(const _Float16* __restrict__ A, int lda, size_t aStride,
              const _Float16* __restrict__ Bt, size_t btStride,
              const float* __restrict__ bias, size_t biasStride,
              _Float16* __restrict__ C, int ldc, size_t cStride, int nCol) {
    const int z = blockIdx.y;
    A += z * aStride; Bt += z * btStride; bias += z * biasStride; C += z * cStride;

    const int nRow = gridDim.x / nCol;
    const int R = nRow < 64 ? nRow : 64;
    const int bid = blockIdx.x;
    const int bandSz = R * nCol;
    const int band = bid / bandSz;
    const int rem = bid % bandSz;
    const int colT = rem / R;
    const int rowT = band * R + (rem % R);
    const int row0 = rowT * 256, col0 = colT * 256;

    // [slot][A/B][256 rows][64 f16] = 128 KiB
    __shared__ _Float16 smem[2][2][256][64];

    const int tid = threadIdx.x;
    const int wave = tid >> 6, lane = tid & 63;
    const int wm2 = (wave & 1) * 128;     // M half of this wave
    const int wn4 = (wave >> 1) * 64;     // N quarter of this wave
    const int m = lane & 15, q = lane >> 4;

    // staging: thread -> (row sr per 64-row pass, 16B-block sb), swizzled src
    const int sr = tid >> 3;
    const int sb = tid & 7;
    const int sblk = sb ^ (sr & 7);       // (row&7)==(sr&7) for every pass

    const _Float16* Asrc = A + (size_t)(row0 + sr) * lda + sblk * 8;
    const _Float16* Bsrc = Bt + (size_t)(col0 + sr) * E_DIM + sblk * 8;
    const size_t aPass = (size_t)64 * lda;   // 64 rows per pass
    const size_t bPass = (size_t)64 * E_DIM;

#define SLOTA(T) ((char*)&smem[(T) & 1][0][0][0] + wave * 1024)
#define SLOTB(T) ((char*)&smem[(T) & 1][1][0][0] + wave * 1024)
#define STAGE_A(T, p) gload_lds16(Asrc + (size_t)(p) * aPass + (T) * 64, SLOTA(T) + (p) * 8192)
#define STAGE_B(T, p) gload_lds16(Bsrc + (size_t)(p) * bPass + (T) * 64, SLOTB(T) + (p) * 8192)
#define STAGE_TILE(T)                                                         \
    {                                                                         \
        STAGE_B(T, 0); STAGE_B(T, 1); STAGE_B(T, 2); STAGE_B(T, 3);           \
        STAGE_A(T, 0); STAGE_A(T, 1); STAGE_A(T, 2); STAGE_A(T, 3);           \
    }

    f32x4 acc[8][4];
#pragma unroll
    for (int i = 0; i < 8; ++i)
#pragma unroll
        for (int j = 0; j < 4; ++j) acc[i][j] = (f32x4){0.f, 0.f, 0.f, 0.f};

    // element offsets of the two kk sub-steps (in f16), swizzled
    const int c0k = ((q) ^ (m & 7)) * 8;
    const int c1k = ((4 + q) ^ (m & 7)) * 8;

    // prologue: tiles 0 and 1 fully staged
    STAGE_TILE(0);
    STAGE_TILE(1);
    asm volatile("s_waitcnt vmcnt(8)" ::: "memory");   // tile0 landed
    __builtin_amdgcn_s_barrier();

    for (int t = 0; t < 8; ++t) {
        const _Float16* As = &smem[t & 1][0][0][0];
        const _Float16* Bs = &smem[t & 1][1][0][0];
        f16x8 b0[4], b1[4];
        f16x8 aA[4], aB[4], aC[4], aD[4];

        // R0: b0 + a fr0-3 @k0
#pragma unroll
        for (int fc = 0; fc < 4; ++fc)
            b0[fc] = *(const f16x8*)&Bs[(wn4 + fc * 16 + m) * 64 + c0k];
#pragma unroll
        for (int i = 0; i < 4; ++i)
            aA[i] = *(const f16x8*)&As[(wm2 + i * 16 + m) * 64 + c0k];
        // R1: a fr4-7 @k0
#pragma unroll
        for (int i = 0; i < 4; ++i)
            aB[i] = *(const f16x8*)&As[(wm2 + (4 + i) * 16 + m) * 64 + c0k];

        // MFMA ph0 (compiler waits only on R0)
        __builtin_amdgcn_s_setprio(1);
#pragma unroll
        for (int i = 0; i < 4; ++i)
#pragma unroll
            for (int fc = 0; fc < 4; ++fc)
                acc[i][fc] = __builtin_amdgcn_mfma_f32_16x16x32_f16(aA[i], b0[fc], acc[i][fc], 0, 0, 0);
        __builtin_amdgcn_s_setprio(0);

        // R2: b1 + a fr0-3 @k1
#pragma unroll
        for (int fc = 0; fc < 4; ++fc)
            b1[fc] = *(const f16x8*)&Bs[(wn4 + fc * 16 + m) * 64 + c1k];
#pragma unroll
        for (int i = 0; i < 4; ++i)
            aC[i] = *(const f16x8*)&As[(wm2 + i * 16 + m) * 64 + c1k];

        // MFMA ph1
        __builtin_amdgcn_s_setprio(1);
#pragma unroll
        for (int i = 0; i < 4; ++i)
#pragma unroll
            for (int fc = 0; fc < 4; ++fc)
                acc[4 + i][fc] = __builtin_amdgcn_mfma_f32_16x16x32_f16(aB[i], b0[fc], acc[4 + i][fc], 0, 0, 0);
        __builtin_amdgcn_s_setprio(0);

        // R3: a fr4-7 @k1
#pragma unroll
        for (int i = 0; i < 4; ++i)
            aD[i] = *(const f16x8*)&As[(wm2 + (4 + i) * 16 + m) * 64 + c1k];

        // MFMA ph2
        __builtin_amdgcn_s_setprio(1);
#pragma unroll
        for (int i = 0; i < 4; ++i)
#pragma unroll
            for (int fc = 0; fc < 4; ++fc)
                acc[i][fc] = __builtin_amdgcn_mfma_f32_16x16x32_f16(aC[i], b1[fc], acc[i][fc], 0, 0, 0);
        __builtin_amdgcn_s_setprio(0);

        // all reads of slot t&1 complete -> safe to restage it after barrier
        asm volatile("s_waitcnt lgkmcnt(0)" ::: "memory");
        __builtin_amdgcn_s_barrier();                 // #1

        if (t < 6) STAGE_TILE(t + 2);                 // into just-freed slot

        // MFMA ph3 (registers only)
        __builtin_amdgcn_s_setprio(1);
#pragma unroll
        for (int i = 0; i < 4; ++i)
#pragma unroll
            for (int fc = 0; fc < 4; ++fc)
                acc[4 + i][fc] = __builtin_amdgcn_mfma_f32_16x16x32_f16(aD[i], b1[fc], acc[4 + i][fc], 0, 0, 0);
        __builtin_amdgcn_s_setprio(0);

        // tile t+1 must be resident before any wave reads it next iteration
        if (t < 6)       asm volatile("s_waitcnt vmcnt(8)" ::: "memory");
        else if (t == 6) asm volatile("s_waitcnt vmcnt(0)" ::: "memory");
        __builtin_amdgcn_s_barrier();                 // #2
    }
#undef STAGE_TILE
#undef STAGE_A
#undef STAGE_B
#undef SLOTA
#undef SLOTB

    // C/D layout: col = lane&15, row = (lane>>4)*4 + reg
#pragma unroll
    for (int fr = 0; fr < 8; ++fr) {
        const int rbase = row0 + wm2 + fr * 16 + q * 4;
#pragma unroll
        for (int fc = 0; fc < 4; ++fc) {
            const int col = col0 + wn4 + fc * 16 + m;
            const float bv = bias[col];
#pragma unroll
            for (int r = 0; r < 4; ++r)
                C[(size_t)(rbase + r) * ldc + col] = (_Float16)(acc[fr][fc][r] + bv);
        }
    }
}

// ---------------------------------------------------------------------------
// fp32 -> fp16 elementwise (vectorized x4)
// ---------------------------------------------------------------------------
__global__ __launch_bounds__(256)
void conv32to16(const float* __restrict__ in, _Float16* __restrict__ out, int n4) {
    int i = blockIdx.x * 256 + threadIdx.x;
    if (i < n4) {
        f32x4 v = ((const f32x4*)in)[i];
        f16x4 o = {(_Float16)v[0], (_Float16)v[1], (_Float16)v[2], (_Float16)v[3]};
        ((f16x4*)out)[i] = o;
    }
}

// ---------------------------------------------------------------------------
// Batched weight transpose fp32->fp16: z 0..2: W1[l]->W1allT; z 3..5:
// Wk,Wv,Wq -> WkvqT rows 0/512/1024.
// ---------------------------------------------------------------------------
__global__ __launch_bounds__(256)
void transpose_all(const float* __restrict__ W1, const float* __restrict__ Wk,
                   const float* __restrict__ Wv, const float* __restrict__ Wq,
                   _Float16* __restrict__ W1allT, _Float16* __restrict__ WkvqT) {
    const int z = blockIdx.z;
    const float* src;
    _Float16* dst;
    const size_t MSZ = (size_t)E_DIM * E_DIM;
    if (z < 3)       { src = W1 + z * MSZ; dst = W1allT + z * MSZ; }
    else if (z == 3) { src = Wk;           dst = WkvqT; }
    else if (z == 4) { src = Wv;           dst = WkvqT + MSZ; }
    else             { src = Wq;           dst = WkvqT + 2 * MSZ; }

    __shared__ float t[32][33];
    const int k0 = blockIdx.x * 32, n0 = blockIdx.y * 32;
    const int tx = threadIdx.x & 31, ty = threadIdx.x >> 5;
#pragma unroll
    for (int r = 0; r < 32; r += 8)
        t[ty + r][tx] = src[(size_t)(k0 + ty + r) * E_DIM + n0 + tx];
    __syncthreads();
#pragma unroll
    for (int r = 0; r < 32; r += 8)
        dst[(size_t)(n0 + ty + r) * E_DIM + k0 + tx] = (_Float16)t[tx][ty + r];
}

// ---------------------------------------------------------------------------
// Composed biases: bcomp[l][n] for n<512: b2_l@Wk + bk; [512,1024): Wv/bv;
// [1024,1536): Wq/bq.
// ---------------------------------------------------------------------------
__global__ __launch_bounds__(256)
void bias_compose(const float* __restrict__ b2, const float* __restrict__ Wk,
                  const float* __restrict__ Wv, const float* __restrict__ Wq,
                  const float* __restrict__ bk, const float* __restrict__ bv,
                  const float* __restrict__ bq, float* __restrict__ bcomp) {
    const int l = blockIdx.y;
    const int n = blockIdx.x * 256 + threadIdx.x;   // 0..1535
    const float* W; const float* bb; int nn;
    if (n < 512)       { W = Wk; bb = bk; nn = n; }
    else if (n < 1024) { W = Wv; bb = bv; nn = n - 512; }
    else               { W = Wq; bb = bq; nn = n - 1024; }
    float acc = 0.f;
    for (int j = 0; j < E_DIM; ++j)
        acc = fmaf(b2[l * E_DIM + j], W[(size_t)j * E_DIM + nn], acc);
    bcomp[l * 1536 + n] = acc + bb[nn];
}

// ---------------------------------------------------------------------------
// LayerNorm + ReLU over bufPall [N x 1536], all 3 levels in one dispatch.
// ---------------------------------------------------------------------------
__global__ __launch_bounds__(256)
void ln_relu_all(_Float16* __restrict__ P, const float* __restrict__ gamma,
                 const float* __restrict__ beta) {
    const int row = blockIdx.x * 4 + (threadIdx.x >> 6);
    const int l = blockIdx.y;
    const int lane = threadIdx.x & 63;
    _Float16* prow = P + (size_t)row * (L_LEV * E_DIM) + l * E_DIM + lane * 8;
    const float* g = gamma + l * E_DIM + lane * 8;
    const float* b = beta  + l * E_DIM + lane * 8;
    f16x8 v = *(const f16x8*)prow;
    float x[8];
    float s = 0.f, s2 = 0.f;
#pragma unroll
    for (int e = 0; e < 8; ++e) {
        x[e] = (float)v[e];
        s += x[e];
        s2 = fmaf(x[e], x[e], s2);
    }
#pragma unroll
    for (int off = 32; off; off >>= 1) {
        s  += __shfl_xor(s, off);
        s2 += __shfl_xor(s2, off);
    }
    const float mean = s * (1.f / E_DIM);
    const float var  = s2 * (1.f / E_DIM) - mean * mean;
    const float rstd = rsqrtf(var + LN_EPS);
    f32x4 g0 = *(const f32x4*)g;
    f32x4 g1 = *(const f32x4*)(g + 4);
    f32x4 b0 = *(const f32x4*)b;
    f32x4 b1 = *(const f32x4*)(b + 4);
    f16x8 o;
#pragma unroll
    for (int e = 0; e < 4; ++e) {
        o[e]     = (_Float16)fmaxf(fmaf((x[e]     - mean) * rstd, g0[e], b0[e]), 0.f);
        o[e + 4] = (_Float16)fmaxf(fmaf((x[e + 4] - mean) * rstd, g1[e], b1[e]), 0.f);
    }
    *(f16x8*)prow = o;
}

// ---------------------------------------------------------------------------
// Contention-free counting sort
// ---------------------------------------------------------------------------
__global__ __launch_bounds__(256)
void label_block_hist(const int* __restrict__ labels, int* __restrict__ blockCounts) {
    __shared__ int h[C_CLS];
    const int tid = threadIdx.x;
    if (tid < C_CLS) h[tid] = 0;
    __syncthreads();
    atomicAdd(&h[labels[blockIdx.x * 256 + tid]], 1);
    __syncthreads();
    if (tid < C_CLS) blockCounts[blockIdx.x * C_CLS + tid] = h[tid];
}

__global__ __launch_bounds__(64)
void scan_offsets(const int* __restrict__ blockCounts, int* __restrict__ counts,
                  int* __restrict__ offs, int* __restrict__ blockOffs) {
    const int c = threadIdx.x;
    int total = 0;
    for (int b = 0; b < SCAT_BLOCKS; ++b) total += blockCounts[b * C_CLS + c];
    counts[c] = total;
    __shared__ int tot[C_CLS];
    tot[c] = total;
    __syncthreads();
    int off = 0;
    for (int cc = 0; cc < c; ++cc) off += tot[cc];
    offs[c] = off;
    if (c == C_CLS - 1) offs[C_CLS] = off + total;
    int run = off;
    for (int b = 0; b < SCAT_BLOCKS; ++b) {
        blockOffs[b * C_CLS + c] = run;
        run += blockCounts[b * C_CLS + c];
    }
}

__global__ __launch_bounds__(256)
void scatter_sorted(const int* __restrict__ labels, const int* __restrict__ blockOffs,
                    int* __restrict__ members) {
    __shared__ int cur[C_CLS];
    const int tid = threadIdx.x;
    if (tid < C_CLS) cur[tid] = blockOffs[blockIdx.x * C_CLS + tid];
    __syncthreads();
    const int i = blockIdx.x * 256 + tid;
    const int c = labels[i];
    const int p = atomicAdd(&cur[c], 1);
    members[p] = i;
}

__global__ __launch_bounds__(256)
void zero_f32(float* __restrict__ p, int n) {
    int i = blockIdx.x * 256 + threadIdx.x;
    if (i < n) p[i] = 0.f;
}

// ---------------------------------------------------------------------------
// hpart[l][c][split][:] = partial segment-sum of h_l over class members.
// Batched over levels (grid.z); write-based (no atomics, no zero pass).
// ---------------------------------------------------------------------------
__global__ __launch_bounds__(256)
void ctx_partial(const _Float16* __restrict__ P, const int* __restrict__ members,
                 const int* __restrict__ offsets, float* __restrict__ hpart) {
    const int c = blockIdx.x, split = blockIdx.y, l = blockIdx.z;
    const _Float16* src = P + (size_t)l * E_DIM;
    const int tid = threadIdx.x;
    const int wave = tid >> 6, lane = tid & 63;
    const int start = offsets[c], end = offsets[c + 1];
    const int wg = split * 4 + wave;
    const int stride = 4 * CTX_SPLITS;
    const int ld = L_LEV * E_DIM;

    float acc[8];
#pragma unroll
    for (int e = 0; e < 8; ++e) acc[e] = 0.f;

    int i = start + wg;
    for (; i + stride < end; i += 2 * stride) {
        const int n0 = members[i];
        const int n1 = members[i + stride];
        f16x8 r0 = *(const f16x8*)(src + (size_t)n0 * ld + lane * 8);
        f16x8 r1 = *(const f16x8*)(src + (size_t)n1 * ld + lane * 8);
#pragma unroll
        for (int e = 0; e < 8; ++e) acc[e] += (float)r0[e] + (float)r1[e];
    }
    if (i < end) {
        const int n0 = members[i];
        f16x8 r0 = *(const f16x8*)(src + (size_t)n0 * ld + lane * 8);
#pragma unroll
        for (int e = 0; e < 8; ++e) acc[e] += (float)r0[e];
    }

    __shared__ float red[4][64][8];
#pragma unroll
    for (int e = 0; e < 8; ++e) red[wave][lane][e] = acc[e];
    __syncthreads();
    float* dst = hpart + (((size_t)l * C_CLS + c) * CTX_SPLITS + split) * E_DIM;
#pragma unroll
    for (int t = 0; t < 2; ++t) {
        const int col = tid * 2 + t;
        const int ln = col >> 3, e = col & 7;
        dst[col] = red[0][ln][e] + red[1][ln][e] + red[2][ln][e] + red[3][ln][e];
    }
}

// ---------------------------------------------------------------------------
// q[l][c][:] = (mean of h_l over class c) @ (W2_l@Wq) + composed bias.
// Batched over levels (grid.y). Reduces the CTX_SPLITS partials inline.
// ---------------------------------------------------------------------------
__global__ __launch_bounds__(256)
void row_gemm_q(const float* __restrict__ hpart, const int* __restrict__ counts,
                const _Float16* __restrict__ W2compT, const float* __restrict__ bcomp,
                float* __restrict__ q) {
    const int c = blockIdx.x, l = blockIdx.y;
    const int tid = threadIdx.x;
    const float inv = 1.f / (float)counts[c];
    __shared__ float xrow[E_DIM];
    const float* hp = hpart + ((size_t)l * C_CLS + c) * CTX_SPLITS * E_DIM;
    float s0 = 0.f, s1 = 0.f;
#pragma unroll
    for (int s = 0; s < CTX_SPLITS; ++s) {
        s0 += hp[s * E_DIM + tid];
        s1 += hp[s * E_DIM + tid + 256];
    }
    xrow[tid]       = s0 * inv;
    xrow[tid + 256] = s1 * inv;
    __syncthreads();

    const _Float16* Wq = W2compT + (size_t)l * 1536 * E_DIM + (size_t)1024 * E_DIM;
    const float* bias = bcomp + l * 1536 + 1024;
    const int n0 = tid, n1 = tid + 256;
    float a0 = 0.f, a1 = 0.f;
#pragma unroll 4
    for (int k0 = 0; k0 < E_DIM; k0 += 8) {
        f16x8 w0 = *(const f16x8*)(Wq + (size_t)n0 * E_DIM + k0);
        f16x8 w1 = *(const f16x8*)(Wq + (size_t)n1 * E_DIM + k0);
#pragma unroll
        for (int e = 0; e < 8; ++e) {
            const float xv = xrow[k0 + e];
            a0 = fmaf(xv, (float)w0[e], a0);
            a1 = fmaf(xv, (float)w1[e], a1);
        }
    }
    float* qq = q + (size_t)l * C_CLS * E_DIM;
    qq[c * E_DIM + n0] = a0 + bias[n0];
    qq[c * E_DIM + n1] = a1 + bias[n1];
}

// ---------------------------------------------------------------------------
// Segment attention, phase 1. K/V packed: row n = [K(512) | V(512)] in bufKV.
// grid (C, H, ATTN_SPLITS). NOTE: splits/waves beyond the member count are
// legitimately empty (m=-inf); the combine must guard exp(-inf - -inf).
// ---------------------------------------------------------------------------
__global__ __launch_bounds__(256)
void attn_partial(const float* __restrict__ q, const _Float16* __restrict__ kv,
                  const int* __restrict__ members, const int* __restrict__ offsets,
                  float* __restrict__ pm, float* __restrict__ pl,
                  float* __restrict__ po) {
    const int c = blockIdx.x, h = blockIdx.y, s = blockIdx.z;
    const int tid = threadIdx.x;
    const int wave = tid >> 6, lane = tid & 63;
    const int start = offsets[c], end = offsets[c + 1];
    const int g = s * 4 + wave;                 // 0..4*SPLITS-1

    float qv[64];
    const bool active = (start + g * 64) < end;
    if (active) {
        const float* qrow = q + c * E_DIM + h * DHD;
#pragma unroll
        for (int d = 0; d < 64; ++d) qv[d] = qrow[d];
    }

    __shared__ float ps[4][64];
    float m = -INFINITY, lsum = 0.f, out = 0.f; // lane owns output dim `lane`

    for (int ch0 = start + g * 64; ch0 < end; ch0 += 4 * ATTN_SPLITS * 64) {
        const int nvalid = min(64, end - ch0);
        const int idx = ch0 + lane;
        const int mi = members[idx < end ? idx : end - 1];
        const _Float16* krow = kv + (size_t)mi * KV_LD + h * DHD;
        float dot = 0.f;
#pragma unroll
        for (int j = 0; j < 8; ++j) {
            f16x8 kr = *(const f16x8*)(krow + j * 8);
#pragma unroll
            for (int e = 0; e < 8; ++e)
                dot = fmaf((float)kr[e], qv[j * 8 + e], dot);
        }
        float sc = (lane < nvalid) ? dot * 0.125f : -INFINITY;
        float cm = sc;
#pragma unroll
        for (int off = 32; off; off >>= 1) cm = fmaxf(cm, __shfl_xor(cm, off));
        const float nm = fmaxf(m, cm);
        const float alpha = __expf(m - nm);
        const float p = (lane < nvalid) ? __expf(sc - nm) : 0.f;
        ps[wave][lane] = p;
        out *= alpha;
        lsum *= alpha;
        m = nm;
        asm volatile("" ::: "memory");
#pragma unroll 16
        for (int j = 0; j < 64; ++j) {
            const int nj = __shfl(mi, j);
            const float pj = ps[wave][j];
            const float vv = (float)kv[(size_t)nj * KV_LD + E_DIM + h * DHD + lane];
            out = fmaf(pj, vv, out);
            lsum += pj;
        }
    }

    __shared__ float rm[4], rl[4], racc[4][64];
    racc[wave][lane] = out;
    if (lane == 0) { rm[wave] = m; rl[wave] = lsum; }
    __syncthreads();
    if (wave == 0) {
        float M = fmaxf(fmaxf(rm[0], rm[1]), fmaxf(rm[2], rm[3]));
        float o = 0.f, Lt = 0.f;
#pragma unroll
        for (int w = 0; w < 4; ++w) {
            // guard: rm[w]==-inf (empty wave) AND possibly M==-inf (all empty)
            // -> exp(-inf - -inf) = NaN without the guard. [R10 NaN bug]
            const float al = (rm[w] > -INFINITY) ? __expf(rm[w] - M) : 0.f;
            o  += al * racc[w][lane];
            Lt += al * rl[w];
        }
        const int pidx = (c * H_HEADS + h) * ATTN_SPLITS + s;
        po[pidx * 64 + lane] = o;      // 0 for all-empty block
        if (lane == 0) { pm[pidx] = M; pl[pidx] = Lt; }
    }
}

// ---------------------------------------------------------------------------
// Combine ATTN_SPLITS partials for all 8 heads of class c into LDS xrow,
// then proto = xrow @ Wo + bo; out (+)= coef_l * proto.
// ---------------------------------------------------------------------------
__global__ __launch_bounds__(256)
void proto_accum(const float* __restrict__ pm, const float* __restrict__ pl,
                 const float* __restrict__ po, const float* __restrict__ Wo,
                 const float* __restrict__ bo, const float* __restrict__ lvlw,
                 const float* __restrict__ lvlt, int l, float* __restrict__ out) {
    const int c = blockIdx.x;
    const int tid = threadIdx.x;
    const int wave = tid >> 6, lane = tid & 63;
    __shared__ float xrow[E_DIM];
#pragma unroll
    for (int hh = wave; hh < H_HEADS; hh += 4) {
        const int ch = c * H_HEADS + hh;
        float M = -INFINITY;
#pragma unroll
        for (int s = 0; s < ATTN_SPLITS; ++s) M = fmaxf(M, pm[ch * ATTN_SPLITS + s]);
        float o = 0.f, Lt = 0.f;
#pragma unroll
        for (int s = 0; s < ATTN_SPLITS; ++s) {
            const int pidx = ch * ATTN_SPLITS + s;
            // guard empty split: pm=-inf -> weight 0 (avoids 0*NaN / exp NaN)
            const float al = (pm[pidx] > -INFINITY) ? __expf(pm[pidx] - M) : 0.f;
            o  += al * po[pidx * 64 + lane];
            Lt += al * pl[pidx];
        }
        xrow[hh * 64 + lane] = o / Lt;
    }
    __syncthreads();

    float a0 = 0.f, a1 = 0.f;
#pragma unroll 8
    for (int k = 0; k < E_DIM; ++k) {
        float cv = xrow[k];
        a0 = fmaf(cv, Wo[(size_t)k * E_DIM + tid], a0);
        a1 = fmaf(cv, Wo[(size_t)k * E_DIM + tid + 256], a1);
    }
    float w0 = lvlw[0], w1 = lvlw[1], w2 = lvlw[2];
    float mx = fmaxf(w0, fmaxf(w1, w2));
    float e0 = expf(w0 - mx), e1 = expf(w1 - mx), e2 = expf(w2 - mx);
    float ssum = e0 + e1 + e2;
    float lw = (l == 0 ? e0 : (l == 1 ? e1 : e2)) / ssum;
    float coef = lw / lvlt[l];
    float r0 = (a0 + bo[tid]) * coef;
    float r1 = (a1 + bo[tid + 256]) * coef;
    if (l == 0) {
        out[c * E_DIM + tid]       = r0;
        out[c * E_DIM + tid + 256] = r1;
    } else {
        out[c * E_DIM + tid]       += r0;
        out[c * E_DIM + tid + 256] += r1;
    }
}

// ---------------------------------------------------------------------------
extern "C" void kernel_launch(void* const* d_in, const int* in_sizes, int n_in,
                              void* d_out, int out_size, void* d_ws, size_t ws_size,
                              hipStream_t stream) {
    const float* X      = (const float*)d_in[0];
    const int*   labels = (const int*)  d_in[1];
    const float* W1     = (const float*)d_in[2];
    const float* b1     = (const float*)d_in[3];   // [3,512] flat == fused bias
    const float* gamma  = (const float*)d_in[4];
    const float* beta   = (const float*)d_in[5];
    const float* W2     = (const float*)d_in[6];
    const float* b2     = (const float*)d_in[7];
    const float* Wq     = (const float*)d_in[8];
    const float* bq     = (const float*)d_in[9];
    const float* Wk     = (const float*)d_in[10];
    const float* bk     = (const float*)d_in[11];
    const float* Wv     = (const float*)d_in[12];
    const float* bv     = (const float*)d_in[13];
    const float* Wo     = (const float*)d_in[14];
    const float* bo     = (const float*)d_in[15];
    const float* lvlw   = (const float*)d_in[16];
    const float* lvlt   = (const float*)d_in[17];
    float* out = (float*)d_out;

    // Workspace carve (~401 MB of the 512 MiB ws)
    char* p = (char*)d_ws;
    const size_t MSZ = (size_t)E_DIM * E_DIM;                       // 262144
    _Float16* Xh      = (_Float16*)p; p += (size_t)N_SUP * E_DIM * 2;         // 64 MB
    _Float16* bufPall = (_Float16*)p; p += (size_t)N_SUP * E_DIM * L_LEV * 2; // 192 MB
    _Float16* bufKV   = (_Float16*)p; p += (size_t)N_SUP * KV_LD * 2;         // 128 MB
    _Float16* W1allT  = (_Float16*)p; p += L_LEV * MSZ * 2;
    _Float16* WkvqT   = (_Float16*)p; p += 3 * MSZ * 2;
    _Float16* W2f16   = (_Float16*)p; p += L_LEV * MSZ * 2;
    _Float16* W2compT = (_Float16*)p; p += (size_t)L_LEV * 1536 * E_DIM * 2;
    float* zeros512 = (float*)p; p += E_DIM * sizeof(float);
    float* bcomp = (float*)p; p += L_LEV * 1536 * sizeof(float);
    float* hpart = (float*)p; p += (size_t)L_LEV * C_CLS * CTX_SPLITS * E_DIM * sizeof(float); // 6 MB
    float* qb    = (float*)p; p += (size_t)L_LEV * C_CLS * E_DIM * sizeof(float);
    float* pm    = (float*)p; p += C_CLS * H_HEADS * ATTN_SPLITS * sizeof(float);
    float* pl    = (float*)p; p += C_CLS * H_HEADS * ATTN_SPLITS * sizeof(float);
    float* po    = (float*)p; p += (size_t)C_CLS * H_HEADS * ATTN_SPLITS * 64 * sizeof(float);
    int* counts      = (int*)p; p += 256;
    int* offs        = (int*)p; p += 512;
    int* members     = (int*)p; p += (size_t)N_SUP * sizeof(int);
    int* blockCounts = (int*)p; p += (size_t)SCAT_BLOCKS * C_CLS * sizeof(int);
    int* blockOffs   = (int*)p; p += (size_t)SCAT_BLOCKS * C_CLS * sizeof(int);

    // Class membership: contention-free counting sort
    label_block_hist<<<SCAT_BLOCKS, 256, 0, stream>>>(labels, blockCounts);
    scan_offsets<<<1, 64, 0, stream>>>(blockCounts, counts, offs, blockOffs);
    scatter_sorted<<<SCAT_BLOCKS, 256, 0, stream>>>(labels, blockOffs, members);

    // Conversions / transposes
    conv32to16<<<(N_SUP * E_DIM / 4) / 256, 256, 0, stream>>>(X, Xh, N_SUP * E_DIM / 4);
    conv32to16<<<(int)(L_LEV * MSZ / 4 / 256), 256, 0, stream>>>(W2, W2f16, L_LEV * MSZ / 4);
    transpose_all<<<dim3(16, 16, 6), 256, 0, stream>>>(W1, Wk, Wv, Wq, W1allT, WkvqT);
    zero_f32<<<2, 256, 0, stream>>>(zeros512, E_DIM);

    // Composed weights: W2compT_l = [WkT;WvT;WqT] @ W2T_l  (fp16 MFMA, batched)
    // M=1536 (6 row-tiles), N=512 (2 col-tiles)
    hgemm256<<<dim3(6 * 2, L_LEV), 512, 0, stream>>>(
        WkvqT, E_DIM, 0, W2f16, MSZ, zeros512, 0,
        W2compT, E_DIM, (size_t)1536 * E_DIM, 2);
    bias_compose<<<dim3(6, L_LEV), 256, 0, stream>>>(b2, Wk, Wv, Wq, bk, bv, bq, bcomp);

    const int nRowT = N_SUP / 256;   // 256 row tiles
    // Fused pre = X @ [W1_0|W1_1|W1_2] + b1  -> bufPall [N x 1536]
    hgemm256<<<dim3(nRowT * 6, 1), 512, 0, stream>>>(
        Xh, E_DIM, 0, W1allT, 0, b1, 0, bufPall, L_LEV * E_DIM, 0, 6);
    // LN+ReLU for all 3 levels (bufPall now holds h)
    ln_relu_all<<<dim3(N_SUP / 4, L_LEV), 256, 0, stream>>>(bufPall, gamma, beta);

    // Level-independent tail, batched once: segment-sum partials + q
    ctx_partial<<<dim3(C_CLS, CTX_SPLITS, L_LEV), 256, 0, stream>>>(
        bufPall, members, offs, hpart);
    row_gemm_q<<<dim3(C_CLS, L_LEV), 256, 0, stream>>>(
        hpart, counts, W2compT, bcomp, qb);

    for (int l = 0; l < L_LEV; ++l) {
        // [K|V] = h_l @ (W2_l@[Wk|Wv]) + composed bias  -> bufKV [N x 1024]
        hgemm256<<<dim3(nRowT * 4, 1), 512, 0, stream>>>(
            bufPall + (size_t)l * E_DIM, L_LEV * E_DIM, 0,
            W2compT + (size_t)l * 1536 * E_DIM, 0,
            bcomp + l * 1536, 0, bufKV, KV_LD, 0, 4);
        attn_partial<<<dim3(C_CLS, H_HEADS, ATTN_SPLITS), 256, 0, stream>>>(
            qb + (size_t)l * C_CLS * E_DIM, bufKV, members, offs, pm, pl, po);
        proto_accum<<<C_CLS, 256, 0, stream>>>(pm, pl, po, Wo, bo, lvlw, lvlt, l, out);
    }
}